// Round 1
// baseline (319.629 us; speedup 1.0000x reference)
//
#include <hip/hip_runtime.h>

#define B_ 2
#define D_ 32
#define C_ 256
#define T_ 64
#define TE_ 1024
#define H_ 8
#define N_ 64   // B_*D_

// ---------------------------------------------------------------- group norm
// x (N,256,64) -> h. One block per (n, group); group = 8 channels x 64 t = 512.
__global__ __launch_bounds__(256) void k_groupnorm(
    const float* __restrict__ x, const float* __restrict__ scale,
    const float* __restrict__ bias, float* __restrict__ h)
{
  int blk = blockIdx.x;           // n*32 + g
  int n = blk >> 5, g = blk & 31;
  const float* xp = x + ((size_t)n*C_ + g*8) * T_;
  float*       hp = h + ((size_t)n*C_ + g*8) * T_;
  int tid = threadIdx.x;
  float v0 = xp[tid], v1 = xp[tid+256];
  float s = v0+v1, ss = v0*v0 + v1*v1;
  #pragma unroll
  for (int off=32; off; off>>=1) { s += __shfl_down(s,off); ss += __shfl_down(ss,off); }
  __shared__ float red[10];
  int wid = tid>>6, lane = tid&63;
  if (lane==0){ red[wid]=s; red[4+wid]=ss; }
  __syncthreads();
  if (tid==0){
    float a  = red[0]+red[1]+red[2]+red[3];
    float b2 = red[4]+red[5]+red[6]+red[7];
    float mean = a*(1.f/512.f);
    float var  = b2*(1.f/512.f) - mean*mean;
    red[8]=mean; red[9]=rsqrtf(var + 1e-5f);
  }
  __syncthreads();
  float mean = red[8], inv = red[9];
  int c0 = g*8 + (tid>>6), c1 = g*8 + ((tid+256)>>6);
  hp[tid]     = (v0-mean)*inv*scale[c0] + bias[c0];
  hp[tid+256] = (v1-mean)*inv*scale[c1] + bias[c1];
}

// ---------------------------------------------------------------- GEMM not
// Out[n,o,t] = sum_c W[o,c]*In[n,c,t] + bias[o] (+ resid). Cin=256, T=64.
// Block: (n, o-block of 64). 256 thr: t=tid&63, wave-uniform oq -> 16 o each.
__global__ __launch_bounds__(256) void k_gemm(
    const float* __restrict__ In, const float* __restrict__ W,
    const float* __restrict__ bias, const float* __restrict__ resid,
    float* __restrict__ Out, int oblocks, int CoutTotal)
{
  __shared__ float lin[256*64];   // 64 KB: In[n] staged (c,t)
  int blk = blockIdx.x;
  int n = blk / oblocks, ob = blk - n*oblocks;
  int tid = threadIdx.x;
  const float* ip = In + (size_t)n*(256*64);
  #pragma unroll 8
  for (int r=0;r<64;r++) lin[r*256+tid] = ip[r*256+tid];
  __syncthreads();
  int t  = tid & 63;
  int oq = __builtin_amdgcn_readfirstlane(tid >> 6);   // wave-uniform -> s_load W
  int obase = ob*64 + oq*16;
  float acc[16];
  #pragma unroll
  for (int j=0;j<16;j++) acc[j]=0.f;
  const float* wrow = W + (size_t)obase*256;
  #pragma unroll 4
  for (int c=0;c<256;c++){
    float hv = lin[c*64+t];
    #pragma unroll
    for (int j=0;j<16;j++) acc[j] = fmaf(wrow[(size_t)j*256 + c], hv, acc[j]);
  }
  size_t outb = ((size_t)n*CoutTotal + obase)*64 + t;
  #pragma unroll
  for (int j=0;j<16;j++){
    float v = acc[j] + bias[obase+j];
    if (resid) v += resid[outb + (size_t)j*64];
    Out[outb + (size_t)j*64] = v;
  }
}

// ---------------------------------------------------------------- scores
// scores[n,h,t,s] = (1/sqrt(32)) * sum_cq q[cq,t]*k[cq,s];  q row o=cq*8+h, k o=256+cq*8+h
__global__ __launch_bounds__(256) void k_scores(
    const float* __restrict__ qkv, float* __restrict__ scores)
{
  int blk = blockIdx.x;          // n*8 + h
  int n = blk >> 3, hh = blk & 7;
  __shared__ float qs[32*64], ks[32*64];
  int tid = threadIdx.x;
  const float* base = qkv + (size_t)n*(768*64);
  for (int i=tid; i<2048; i+=256){
    int cq = i>>6, tt = i&63;
    qs[i] = base[(cq*8+hh)*64 + tt];
    ks[i] = base[(256 + cq*8+hh)*64 + tt];
  }
  __syncthreads();
  int s  = tid & 63;
  int t4 = __builtin_amdgcn_readfirstlane(tid>>6);
  float acc[16];
  #pragma unroll
  for (int j=0;j<16;j++) acc[j]=0.f;
  for (int cq=0;cq<32;cq++){
    float kv = ks[cq*64+s];
    #pragma unroll
    for (int j=0;j<16;j++) acc[j] = fmaf(qs[cq*64 + t4*16 + j], kv, acc[j]);
  }
  float* op = scores + (size_t)blk*4096;
  const float sc = 0.17677669529663687f; // 1/sqrt(32)
  #pragma unroll
  for (int j=0;j<16;j++) op[(t4*16+j)*64 + s] = acc[j]*sc;
}

// ---------------------------------------------------------------- temb proj
// tp[b,o,t] = sum_e temb[b,e,t]*w2[o,e] + b2[o]
__global__ __launch_bounds__(256) void k_tproj(
    const float* __restrict__ temb, const float* __restrict__ w2,
    const float* __restrict__ b2, float* __restrict__ tp)
{
  int blk = blockIdx.x;        // b*32 + obk (8 o's each)
  int b = blk >> 5, obk = blk & 31;
  int tid = threadIdx.x;
  int t  = tid & 63;
  int eq = __builtin_amdgcn_readfirstlane(tid >> 6);
  const float* te = temb + (size_t)b*(TE_*64);
  float acc[8];
  #pragma unroll
  for (int j=0;j<8;j++) acc[j]=0.f;
  for (int e=eq; e<1024; e+=4){
    float tv = te[e*64 + t];
    #pragma unroll
    for (int j=0;j<8;j++) acc[j] = fmaf(w2[(size_t)(obk*8+j)*1024 + e], tv, acc[j]);
  }
  __shared__ float red[4][8][64];
  #pragma unroll
  for (int j=0;j<8;j++) red[eq][j][t] = acc[j];
  __syncthreads();
  if (tid < 64){
    #pragma unroll
    for (int j=0;j<8;j++){
      float v = red[0][j][t]+red[1][j][t]+red[2][j][t]+red[3][j][t];
      int o = obk*8+j;
      tp[((size_t)b*256+o)*64 + t] = v + b2[o];
    }
  }
}

// ---------------------------------------------------------------- wa
// wa[b,o,t,s] = sum_i w3[o,i]*relu(w1[i,:]·(l0,l1,l2)[s] + b1[i] + tp[b,i,t]) + b3[o]
// block = (b, t, ob of 64 o's); E staged in 2 chunks of 128 channels, XOR-swizzled.
__global__ __launch_bounds__(256) void k_wa(
    const int* __restrict__ fi, const float* __restrict__ w1,
    const float* __restrict__ b1, const float* __restrict__ tp,
    const float* __restrict__ w3, const float* __restrict__ b3,
    float* __restrict__ wa)
{
  int blk = blockIdx.x;       // ((b*64 + t)*4 + ob)
  int ob = blk & 3; int bt = blk >> 2;
  int b = bt >> 6, t = bt & 63;
  __shared__ float l0[64], l1[64], l2[64];
  __shared__ float E[128*64]; // [i][s^(i&31)]
  int tid = threadIdx.x;
  if (tid < 64){
    int rel = fi[b*64+tid] - fi[b*64+t];
    float r0 = rel>0 ? (float)rel   : 0.f;
    float r1 = rel<0 ? (float)(-rel): 0.f;
    l0[tid] = log1pf(r0);
    l1[tid] = log1pf(r1);
    l2[tid] = (rel==0) ? 0.6931471805599453f : 0.f;
  }
  int s  = tid & 63;
  int oq = __builtin_amdgcn_readfirstlane(tid>>6);
  int obase = ob*64 + oq*16;
  float acc[16];
  #pragma unroll
  for (int j=0;j<16;j++) acc[j]=0.f;
  int il  = tid >> 1;
  int sh0 = (tid & 1) * 32;
  __syncthreads();
  for (int ch=0; ch<2; ch++){
    int i = ch*128 + il;
    float wv0 = w1[i*3], wv1 = w1[i*3+1], wv2 = w1[i*3+2];
    float bb  = b1[i] + tp[((size_t)b*256 + i)*64 + t];
    #pragma unroll
    for (int k=0;k<32;k++){
      int ss = sh0 + k;
      float e = fmaf(wv0,l0[ss], fmaf(wv1,l1[ss], fmaf(wv2,l2[ss], bb)));
      E[il*64 + (ss ^ (il & 31))] = fmaxf(e, 0.f);
    }
    __syncthreads();
    const float* w3r = w3 + (size_t)obase*256 + ch*128;
    #pragma unroll 2
    for (int ii=0; ii<128; ii++){
      float ev = E[ii*64 + (s ^ (ii & 31))];
      #pragma unroll
      for (int j=0;j<16;j++) acc[j] = fmaf(w3r[(size_t)j*256 + ii], ev, acc[j]);
    }
    __syncthreads();
  }
  float* op = wa + (size_t)(b*256 + obase)*4096 + t*64 + s;
  #pragma unroll
  for (int j=0;j<16;j++) op[(size_t)j*4096] = acc[j] + b3[obase+j];
}

// ---------------------------------------------------------------- softmax+PV
// hv[b,d,c,t] = sum_s softmax_s(scores[b,d,c%8,t,s] + wa[b,c,t,s]) * v[b,d,c,s]
// block = (b,h,dq of 4 d's, cs of 8 c's). scores row in regs (reused 8x), wa in LDS.
__global__ __launch_bounds__(256) void k_attn(
    const float* __restrict__ scores, const float* __restrict__ wa,
    const float* __restrict__ qkv, const float* __restrict__ amask,
    float* __restrict__ hv)
{
  int blk = blockIdx.x;  // (((b*8 + h)*8 + dq)*4 + cs)
  int cs = blk & 3; blk >>= 2;
  int dq = blk & 7; blk >>= 3;
  int hh = blk & 7; int b = blk >> 3;
  int tid = threadIdx.x;
  int t  = tid & 63;
  int dj = __builtin_amdgcn_readfirstlane(tid >> 6);
  int n  = b*D_ + dq*4 + dj;
  const float* sp = scores + ((size_t)(n*8 + hh))*4096 + t*64;
  float srow[64];
  #pragma unroll
  for (int k=0;k<16;k++){
    float4 v4 = *(const float4*)(sp + 4*k);
    srow[4*k]=v4.x; srow[4*k+1]=v4.y; srow[4*k+2]=v4.z; srow[4*k+3]=v4.w;
  }
  __shared__ float wal[64*65];
  __shared__ float vl[4][64];
  __shared__ float ml[64];
  if (tid < 64) ml[tid] = amask[b*64 + tid];
  for (int ci=0; ci<8; ci++){
    int c = (cs*8 + ci)*8 + hh;        // c % 8 == hh
    __syncthreads();
    const float* wap = wa + ((size_t)(b*256 + c))*4096;
    for (int k2=tid; k2<4096; k2+=256)
      wal[(k2>>6)*65 + (k2&63)] = wap[k2];
    {
      int j = tid >> 6, ss = tid & 63;
      vl[j][ss] = qkv[(size_t)(b*D_ + dq*4 + j)*(768*64) + (512+c)*64 + ss];
    }
    __syncthreads();
    float sum = 0.f, acc = 0.f;
    #pragma unroll
    for (int s=0;s<64;s++){
      float w = srow[s] + wal[t*65 + s];
      float p = (ml[s] > 0.f) ? __expf(w) : 0.f;  // |w|<~10 -> no max-shift needed in fp32
      sum += p;
      acc = fmaf(p, vl[dj][s], acc);
    }
    hv[((size_t)n*256 + c)*64 + t] = acc / sum;
  }
}

extern "C" void kernel_launch(void* const* d_in, const int* in_sizes, int n_in,
                              void* d_out, int out_size, void* d_ws, size_t ws_size,
                              hipStream_t stream) {
  const float* x     = (const float*)d_in[0];
  const float* temb  = (const float*)d_in[1];
  const int*   fi    = (const int*)  d_in[2];
  const float* amask = (const float*)d_in[3];
  const float* nsc   = (const float*)d_in[4];
  const float* nbi   = (const float*)d_in[5];
  const float* w_qkv = (const float*)d_in[6];
  const float* b_qkv = (const float*)d_in[7];
  const float* w1    = (const float*)d_in[8];
  const float* b1    = (const float*)d_in[9];
  const float* w2    = (const float*)d_in[10];
  const float* b2    = (const float*)d_in[11];
  const float* w3    = (const float*)d_in[12];
  const float* b3    = (const float*)d_in[13];
  const float* wp    = (const float*)d_in[14];
  const float* bp    = (const float*)d_in[15];
  float* out = (float*)d_out;
  float* ws  = (float*)d_ws;

  float* h      = ws;                    // 1,048,576
  float* qkv    = h      + 1048576;      // 3,145,728
  float* scores = qkv    + 3145728;      // 2,097,152
  float* tp     = scores + 2097152;      //    32,768
  float* wab    = tp     + 32768;        // 2,097,152
  float* hv     = wab    + 2097152;      // 1,048,576  (total ~38 MB)

  k_groupnorm<<<N_*32, 256, 0, stream>>>(x, nsc, nbi, h);
  k_gemm     <<<N_*12, 256, 0, stream>>>(h, w_qkv, b_qkv, nullptr, qkv, 12, 768);
  k_scores   <<<N_*8,  256, 0, stream>>>(qkv, scores);
  k_tproj    <<<B_*32, 256, 0, stream>>>(temb, w2, b2, tp);
  k_wa       <<<B_*T_*4, 256, 0, stream>>>(fi, w1, b1, tp, w3, b3, wab);
  k_attn     <<<B_*H_*8*4, 256, 0, stream>>>(scores, wab, qkv, amask, hv);
  k_gemm     <<<N_*4,  256, 0, stream>>>(hv, wp, bp, x, out, 4, 256);
}

// Round 2
// 218.929 us; speedup vs baseline: 1.4600x; 1.4600x over previous
//
#include <hip/hip_runtime.h>

#define B_ 2
#define D_ 32
#define C_ 256
#define T_ 64
#define TE_ 1024
#define H_ 8
#define N_ 64   // B_*D_

// ---------------------------------------------------------------- group norm
// x (N,256,64) -> h. One block per (n, group); group = 8 channels x 64 t = 512.
__global__ __launch_bounds__(256) void k_groupnorm(
    const float* __restrict__ x, const float* __restrict__ scale,
    const float* __restrict__ bias, float* __restrict__ h)
{
  int blk = blockIdx.x;           // n*32 + g
  int n = blk >> 5, g = blk & 31;
  const float* xp = x + ((size_t)n*C_ + g*8) * T_;
  float*       hp = h + ((size_t)n*C_ + g*8) * T_;
  int tid = threadIdx.x;
  float v0 = xp[tid], v1 = xp[tid+256];
  float s = v0+v1, ss = v0*v0 + v1*v1;
  #pragma unroll
  for (int off=32; off; off>>=1) { s += __shfl_down(s,off); ss += __shfl_down(ss,off); }
  __shared__ float red[10];
  int wid = tid>>6, lane = tid&63;
  if (lane==0){ red[wid]=s; red[4+wid]=ss; }
  __syncthreads();
  if (tid==0){
    float a  = red[0]+red[1]+red[2]+red[3];
    float b2 = red[4]+red[5]+red[6]+red[7];
    float mean = a*(1.f/512.f);
    float var  = b2*(1.f/512.f) - mean*mean;
    red[8]=mean; red[9]=rsqrtf(var + 1e-5f);
  }
  __syncthreads();
  float mean = red[8], inv = red[9];
  int c0 = g*8 + (tid>>6), c1 = g*8 + ((tid+256)>>6);
  hp[tid]     = (v0-mean)*inv*scale[c0] + bias[c0];
  hp[tid+256] = (v1-mean)*inv*scale[c1] + bias[c1];
}

// ---------------------------------------------------------------- GEMM not
// Out[n,o,t] = sum_c W[o,c]*In[n,c,t] + bias[o] (+ resid). Cin=256, T=64.
// Block: (n, o-block of 64). 256 thr: t=tid&63, wave-uniform oq -> 16 o each.
__global__ __launch_bounds__(256) void k_gemm(
    const float* __restrict__ In, const float* __restrict__ W,
    const float* __restrict__ bias, const float* __restrict__ resid,
    float* __restrict__ Out, int oblocks, int CoutTotal)
{
  __shared__ float lin[256*64];   // 64 KB: In[n] staged (c,t)
  int blk = blockIdx.x;
  int n = blk / oblocks, ob = blk - n*oblocks;
  int tid = threadIdx.x;
  const float* ip = In + (size_t)n*(256*64);
  #pragma unroll 8
  for (int r=0;r<64;r++) lin[r*256+tid] = ip[r*256+tid];
  __syncthreads();
  int t  = tid & 63;
  int oq = __builtin_amdgcn_readfirstlane(tid >> 6);   // wave-uniform -> s_load W
  int obase = ob*64 + oq*16;
  float acc[16];
  #pragma unroll
  for (int j=0;j<16;j++) acc[j]=0.f;
  const float* wrow = W + (size_t)obase*256;
  #pragma unroll 4
  for (int c=0;c<256;c++){
    float hv = lin[c*64+t];
    #pragma unroll
    for (int j=0;j<16;j++) acc[j] = fmaf(wrow[(size_t)j*256 + c], hv, acc[j]);
  }
  size_t outb = ((size_t)n*CoutTotal + obase)*64 + t;
  #pragma unroll
  for (int j=0;j<16;j++){
    float v = acc[j] + bias[obase+j];
    if (resid) v += resid[outb + (size_t)j*64];
    Out[outb + (size_t)j*64] = v;
  }
}

// ---------------------------------------------------------------- scores
// scores[n,h,t,s] = (1/sqrt(32)) * sum_cq q[cq,t]*k[cq,s];  q row o=cq*8+h, k o=256+cq*8+h
__global__ __launch_bounds__(256) void k_scores(
    const float* __restrict__ qkv, float* __restrict__ scores)
{
  int blk = blockIdx.x;          // n*8 + h
  int n = blk >> 3, hh = blk & 7;
  __shared__ float qs[32*64], ks[32*64];
  int tid = threadIdx.x;
  const float* base = qkv + (size_t)n*(768*64);
  for (int i=tid; i<2048; i+=256){
    int cq = i>>6, tt = i&63;
    qs[i] = base[(cq*8+hh)*64 + tt];
    ks[i] = base[(256 + cq*8+hh)*64 + tt];
  }
  __syncthreads();
  int s  = tid & 63;
  int t4 = __builtin_amdgcn_readfirstlane(tid>>6);
  float acc[16];
  #pragma unroll
  for (int j=0;j<16;j++) acc[j]=0.f;
  for (int cq=0;cq<32;cq++){
    float kv = ks[cq*64+s];
    #pragma unroll
    for (int j=0;j<16;j++) acc[j] = fmaf(qs[cq*64 + t4*16 + j], kv, acc[j]);
  }
  float* op = scores + (size_t)blk*4096;
  const float sc = 0.17677669529663687f; // 1/sqrt(32)
  #pragma unroll
  for (int j=0;j<16;j++) op[(t4*16+j)*64 + s] = acc[j]*sc;
}

// ---------------------------------------------------------------- temb proj
// tp[b,o,t] = sum_e temb[b,e,t]*w2[o,e] + b2[o]
// grid = B*64: blk = b*64 + ob (4 o's each). 256 thr = t(64) x eq(4, K-split).
// w2 rows staged in LDS (wave-uniform b128 broadcasts); temb loads pipelined.
__global__ __launch_bounds__(256) void k_tproj(
    const float* __restrict__ temb, const float* __restrict__ w2,
    const float* __restrict__ b2, float* __restrict__ tp)
{
  __shared__ float w2s[4*1024];     // 16 KB [o][e]
  __shared__ float red[4][4][64];   // 4 KB
  int blk = blockIdx.x;
  int b = blk >> 6, ob = blk & 63;
  int tid = threadIdx.x;
  const float* w2p = w2 + (size_t)ob*4*1024;
  #pragma unroll
  for (int r = 0; r < 16; r++) w2s[r*256 + tid] = w2p[r*256 + tid];
  __syncthreads();
  int t = tid & 63, eq = tid >> 6;
  const float* tep = temb + ((size_t)b*1024 + eq*256)*64 + t;
  const float* wq  = w2s + eq*256;
  float acc[4] = {0.f,0.f,0.f,0.f};
  #pragma unroll 4
  for (int i = 0; i < 256; i += 4) {
    float tv0 = tep[(i+0)*64];
    float tv1 = tep[(i+1)*64];
    float tv2 = tep[(i+2)*64];
    float tv3 = tep[(i+3)*64];
    #pragma unroll
    for (int j = 0; j < 4; j++) {
      float4 w4 = *(const float4*)&wq[j*1024 + i];
      acc[j] = fmaf(w4.x, tv0, acc[j]);
      acc[j] = fmaf(w4.y, tv1, acc[j]);
      acc[j] = fmaf(w4.z, tv2, acc[j]);
      acc[j] = fmaf(w4.w, tv3, acc[j]);
    }
  }
  #pragma unroll
  for (int j=0;j<4;j++) red[eq][j][t] = acc[j];
  __syncthreads();
  if (tid < 64) {
    #pragma unroll
    for (int j=0;j<4;j++){
      int o = ob*4 + j;
      float v = red[0][j][tid]+red[1][j][tid]+red[2][j][tid]+red[3][j][tid];
      tp[((size_t)b*256+o)*64 + tid] = v + b2[o];
    }
  }
}

// ---------------------------------------------------------------- wa
// wa[b,o,t,s] = sum_i w3[o,i]*relu(w1[i,:]·(l0,l1,l2)[s] + b1[i] + tp[b,i,t]) + b3[o]
// block = (b, t, ob of 64 o's); E staged in 2 chunks of 128 channels, XOR-swizzled.
__global__ __launch_bounds__(256) void k_wa(
    const int* __restrict__ fi, const float* __restrict__ w1,
    const float* __restrict__ b1, const float* __restrict__ tp,
    const float* __restrict__ w3, const float* __restrict__ b3,
    float* __restrict__ wa)
{
  int blk = blockIdx.x;       // ((b*64 + t)*4 + ob)
  int ob = blk & 3; int bt = blk >> 2;
  int b = bt >> 6, t = bt & 63;
  __shared__ float l0[64], l1[64], l2[64];
  __shared__ float E[128*64]; // [i][s^(i&31)]
  int tid = threadIdx.x;
  if (tid < 64){
    int rel = fi[b*64+tid] - fi[b*64+t];
    float r0 = rel>0 ? (float)rel   : 0.f;
    float r1 = rel<0 ? (float)(-rel): 0.f;
    l0[tid] = log1pf(r0);
    l1[tid] = log1pf(r1);
    l2[tid] = (rel==0) ? 0.6931471805599453f : 0.f;
  }
  int s  = tid & 63;
  int oq = __builtin_amdgcn_readfirstlane(tid>>6);
  int obase = ob*64 + oq*16;
  float acc[16];
  #pragma unroll
  for (int j=0;j<16;j++) acc[j]=0.f;
  int il  = tid >> 1;
  int sh0 = (tid & 1) * 32;
  __syncthreads();
  for (int ch=0; ch<2; ch++){
    int i = ch*128 + il;
    float wv0 = w1[i*3], wv1 = w1[i*3+1], wv2 = w1[i*3+2];
    float bb  = b1[i] + tp[((size_t)b*256 + i)*64 + t];
    #pragma unroll
    for (int k=0;k<32;k++){
      int ss = sh0 + k;
      float e = fmaf(wv0,l0[ss], fmaf(wv1,l1[ss], fmaf(wv2,l2[ss], bb)));
      E[il*64 + (ss ^ (il & 31))] = fmaxf(e, 0.f);
    }
    __syncthreads();
    const float* w3r = w3 + (size_t)obase*256 + ch*128;
    #pragma unroll 2
    for (int ii=0; ii<128; ii++){
      float ev = E[ii*64 + (s ^ (ii & 31))];
      #pragma unroll
      for (int j=0;j<16;j++) acc[j] = fmaf(w3r[(size_t)j*256 + ii], ev, acc[j]);
    }
    __syncthreads();
  }
  float* op = wa + (size_t)(b*256 + obase)*4096 + t*64 + s;
  #pragma unroll
  for (int j=0;j<16;j++) op[(size_t)j*4096] = acc[j] + b3[obase+j];
}

// ---------------------------------------------------------------- softmax+PV
// hv[b,d,c,t] = sum_s softmax_s(scores[b,d,c%8,t,s] + wa[b,c,t,s]) * v[b,d,c,s]
// block = (b,h,dq of 4 d's, cs of 8 c's). scores row in regs (reused 8x), wa in LDS.
__global__ __launch_bounds__(256) void k_attn(
    const float* __restrict__ scores, const float* __restrict__ wa,
    const float* __restrict__ qkv, const float* __restrict__ amask,
    float* __restrict__ hv)
{
  int blk = blockIdx.x;  // (((b*8 + h)*8 + dq)*4 + cs)
  int cs = blk & 3; blk >>= 2;
  int dq = blk & 7; blk >>= 3;
  int hh = blk & 7; int b = blk >> 3;
  int tid = threadIdx.x;
  int t  = tid & 63;
  int dj = __builtin_amdgcn_readfirstlane(tid >> 6);
  int n  = b*D_ + dq*4 + dj;
  const float* sp = scores + ((size_t)(n*8 + hh))*4096 + t*64;
  float srow[64];
  #pragma unroll
  for (int k=0;k<16;k++){
    float4 v4 = *(const float4*)(sp + 4*k);
    srow[4*k]=v4.x; srow[4*k+1]=v4.y; srow[4*k+2]=v4.z; srow[4*k+3]=v4.w;
  }
  __shared__ float wal[64*65];
  __shared__ float vl[4][64];
  __shared__ float ml[64];
  if (tid < 64) ml[tid] = amask[b*64 + tid];
  for (int ci=0; ci<8; ci++){
    int c = (cs*8 + ci)*8 + hh;        // c % 8 == hh
    __syncthreads();
    const float* wap = wa + ((size_t)(b*256 + c))*4096;
    for (int k2=tid; k2<4096; k2+=256)
      wal[(k2>>6)*65 + (k2&63)] = wap[k2];
    {
      int j = tid >> 6, ss = tid & 63;
      vl[j][ss] = qkv[(size_t)(b*D_ + dq*4 + j)*(768*64) + (512+c)*64 + ss];
    }
    __syncthreads();
    float sum = 0.f, acc = 0.f;
    #pragma unroll
    for (int s=0;s<64;s++){
      float w = srow[s] + wal[t*65 + s];
      float p = (ml[s] > 0.f) ? __expf(w) : 0.f;  // |w|<~10 -> no max-shift needed in fp32
      sum += p;
      acc = fmaf(p, vl[dj][s], acc);
    }
    hv[((size_t)n*256 + c)*64 + t] = acc / sum;
  }
}

extern "C" void kernel_launch(void* const* d_in, const int* in_sizes, int n_in,
                              void* d_out, int out_size, void* d_ws, size_t ws_size,
                              hipStream_t stream) {
  const float* x     = (const float*)d_in[0];
  const float* temb  = (const float*)d_in[1];
  const int*   fi    = (const int*)  d_in[2];
  const float* amask = (const float*)d_in[3];
  const float* nsc   = (const float*)d_in[4];
  const float* nbi   = (const float*)d_in[5];
  const float* w_qkv = (const float*)d_in[6];
  const float* b_qkv = (const float*)d_in[7];
  const float* w1    = (const float*)d_in[8];
  const float* b1    = (const float*)d_in[9];
  const float* w2    = (const float*)d_in[10];
  const float* b2    = (const float*)d_in[11];
  const float* w3    = (const float*)d_in[12];
  const float* b3    = (const float*)d_in[13];
  const float* wp    = (const float*)d_in[14];
  const float* bp    = (const float*)d_in[15];
  float* out = (float*)d_out;
  float* ws  = (float*)d_ws;

  float* h      = ws;                    // 1,048,576
  float* qkv    = h      + 1048576;      // 3,145,728
  float* scores = qkv    + 3145728;      // 2,097,152
  float* tp     = scores + 2097152;      //    32,768
  float* wab    = tp     + 32768;        // 2,097,152
  float* hv     = wab    + 2097152;      // 1,048,576  (total ~38 MB)

  k_groupnorm<<<N_*32, 256, 0, stream>>>(x, nsc, nbi, h);
  k_gemm     <<<N_*12, 256, 0, stream>>>(h, w_qkv, b_qkv, nullptr, qkv, 12, 768);
  k_scores   <<<N_*8,  256, 0, stream>>>(qkv, scores);
  k_tproj    <<<B_*64, 256, 0, stream>>>(temb, w2, b2, tp);
  k_wa       <<<B_*T_*4, 256, 0, stream>>>(fi, w1, b1, tp, w3, b3, wab);
  k_attn     <<<B_*H_*8*4, 256, 0, stream>>>(scores, wab, qkv, amask, hv);
  k_gemm     <<<N_*4,  256, 0, stream>>>(hv, wp, bp, x, out, 4, 256);
}

// Round 3
// 124.733 us; speedup vs baseline: 2.5625x; 1.7552x over previous
//
#include <hip/hip_runtime.h>

#define B_ 2
#define D_ 32
#define C_ 256
#define T_ 64
#define TE_ 1024
#define H_ 8
#define N_ 64   // B_*D_

typedef __attribute__((ext_vector_type(8))) short bf16x8;
typedef __attribute__((ext_vector_type(4))) float f32x4;

__device__ inline ushort f2bf(float x){
  unsigned u = __float_as_uint(x);
  unsigned r = u + 0x7FFFu + ((u>>16)&1u);
  return (ushort)(r>>16);
}

// ---------------------------------------------------------------- weight cast
__global__ __launch_bounds__(256) void k_castw(
    const float* __restrict__ src, ushort* __restrict__ dst, int n4)
{
  int i = blockIdx.x*256 + threadIdx.x;
  if (i < n4){
    float4 v = ((const float4*)src)[i];
    ushort4 o; o.x=f2bf(v.x); o.y=f2bf(v.y); o.z=f2bf(v.z); o.w=f2bf(v.w);
    ((ushort4*)dst)[i] = o;
  }
}

// ---------------------------------------------------------------- group norm
// x (N,256,64) -> ht bf16 [n][t][c] (transposed for MFMA B-operand).
__global__ __launch_bounds__(256) void k_groupnorm(
    const float* __restrict__ x, const float* __restrict__ scale,
    const float* __restrict__ bias, ushort* __restrict__ ht)
{
  int blk = blockIdx.x;           // n*32 + g
  int n = blk >> 5, g = blk & 31;
  const float* xp = x + ((size_t)n*C_ + g*8) * T_;
  int tid = threadIdx.x;
  float v0 = xp[tid], v1 = xp[tid+256];
  float s = v0+v1, ss = v0*v0 + v1*v1;
  #pragma unroll
  for (int off=32; off; off>>=1) { s += __shfl_down(s,off); ss += __shfl_down(ss,off); }
  __shared__ float red[10];
  int wid = tid>>6, lane = tid&63;
  if (lane==0){ red[wid]=s; red[4+wid]=ss; }
  __syncthreads();
  if (tid==0){
    float a  = red[0]+red[1]+red[2]+red[3];
    float b2 = red[4]+red[5]+red[6]+red[7];
    float mean = a*(1.f/512.f);
    float var  = b2*(1.f/512.f) - mean*mean;
    red[8]=mean; red[9]=rsqrtf(var + 1e-5f);
  }
  __syncthreads();
  float mean = red[8], inv = red[9];
  int t = tid & 63;
  int c0 = g*8 + (tid>>6), c1 = c0 + 4;
  size_t rowb = ((size_t)n*T_ + t)*C_;
  ht[rowb + c0] = f2bf((v0-mean)*inv*scale[c0] + bias[c0]);
  ht[rowb + c1] = f2bf((v1-mean)*inv*scale[c1] + bias[c1]);
}

// ---------------------------------------------------------------- MFMA GEMM
// Out[n,o,t] = sum_c Wb[o,c]*Inb[n,t,c] + bias[o] (+resid), K=256, bf16 MFMA.
// grid = n * oblocks; 4 waves: wave w -> o-rows [ob*64+w*16, +16), all 64 t.
__global__ __launch_bounds__(256) void k_mm(
    const ushort* __restrict__ Wb, const ushort* __restrict__ Inb,
    const float* __restrict__ bias, const float* __restrict__ resid,
    float* __restrict__ Out, int oblocks, int Ototal)
{
  int blk = blockIdx.x;
  int n = blk / oblocks, ob = blk - n*oblocks;
  int tid = threadIdx.x;
  int lane = tid & 63, w = tid >> 6;
  int o0 = ob*64 + w*16;
  int r = lane & 15, kg = lane >> 4;
  const ushort* wp = Wb + (size_t)(o0 + r)*256 + kg*8;
  const ushort* ip = Inb + ((size_t)n*64 + r)*256 + kg*8;
  f32x4 acc[4];
  #pragma unroll
  for (int j=0;j<4;j++) acc[j] = (f32x4){0.f,0.f,0.f,0.f};
  #pragma unroll
  for (int ks = 0; ks < 8; ks++) {
    bf16x8 a = *(const bf16x8*)(wp + ks*32);
    #pragma unroll
    for (int j = 0; j < 4; j++) {
      bf16x8 b = *(const bf16x8*)(ip + (size_t)j*16*256 + ks*32);
      acc[j] = __builtin_amdgcn_mfma_f32_16x16x32_bf16(a, b, acc[j], 0, 0, 0);
    }
  }
  #pragma unroll
  for (int j = 0; j < 4; j++) {
    #pragma unroll
    for (int rr = 0; rr < 4; rr++) {
      int o = o0 + kg*4 + rr;
      size_t idx = ((size_t)n*Ototal + o)*64 + j*16 + r;
      float v = acc[j][rr] + bias[o];
      if (resid) v += resid[idx];
      Out[idx] = v;
    }
  }
}

// ---------------------------------------------------------------- scores->es
// es[n,h,t,s] = exp((1/sqrt(32)) * sum_cq q[cq,t]*k[cq,s])
__global__ __launch_bounds__(256) void k_scores(
    const float* __restrict__ qkv, float* __restrict__ es)
{
  int blk = blockIdx.x;          // n*8 + h
  int n = blk >> 3, hh = blk & 7;
  __shared__ float qs[32*64], ks[32*64];
  int tid = threadIdx.x;
  const float* base = qkv + (size_t)n*(768*64);
  for (int i=tid; i<2048; i+=256){
    int cq = i>>6, tt = i&63;
    qs[i] = base[(cq*8+hh)*64 + tt];
    ks[i] = base[(256 + cq*8+hh)*64 + tt];
  }
  __syncthreads();
  int s  = tid & 63;
  int t4 = __builtin_amdgcn_readfirstlane(tid>>6);
  float acc[16];
  #pragma unroll
  for (int j=0;j<16;j++) acc[j]=0.f;
  for (int cq=0;cq<32;cq++){
    float kv = ks[cq*64+s];
    #pragma unroll
    for (int j=0;j<16;j++) acc[j] = fmaf(qs[cq*64 + t4*16 + j], kv, acc[j]);
  }
  float* op = es + (size_t)blk*4096;
  const float sc = 0.17677669529663687f; // 1/sqrt(32)
  #pragma unroll
  for (int j=0;j<16;j++) op[(t4*16+j)*64 + s] = __expf(acc[j]*sc);
}

// ---------------------------------------------------------------- temb proj
__global__ __launch_bounds__(256) void k_tproj(
    const float* __restrict__ temb, const float* __restrict__ w2,
    const float* __restrict__ b2, float* __restrict__ tp)
{
  __shared__ float w2s[4*1024];
  __shared__ float red[4][4][64];
  int blk = blockIdx.x;
  int b = blk >> 6, ob = blk & 63;
  int tid = threadIdx.x;
  const float* w2p = w2 + (size_t)ob*4*1024;
  #pragma unroll
  for (int r = 0; r < 16; r++) w2s[r*256 + tid] = w2p[r*256 + tid];
  __syncthreads();
  int t = tid & 63, eq = tid >> 6;
  const float* tep = temb + ((size_t)b*1024 + eq*256)*64 + t;
  const float* wq  = w2s + eq*256;
  float acc[4] = {0.f,0.f,0.f,0.f};
  #pragma unroll 4
  for (int i = 0; i < 256; i += 4) {
    float tv0 = tep[(i+0)*64];
    float tv1 = tep[(i+1)*64];
    float tv2 = tep[(i+2)*64];
    float tv3 = tep[(i+3)*64];
    #pragma unroll
    for (int j = 0; j < 4; j++) {
      float4 w4 = *(const float4*)&wq[j*1024 + i];
      acc[j] = fmaf(w4.x, tv0, acc[j]);
      acc[j] = fmaf(w4.y, tv1, acc[j]);
      acc[j] = fmaf(w4.z, tv2, acc[j]);
      acc[j] = fmaf(w4.w, tv3, acc[j]);
    }
  }
  #pragma unroll
  for (int j=0;j<4;j++) red[eq][j][t] = acc[j];
  __syncthreads();
  if (tid < 64) {
    #pragma unroll
    for (int j=0;j<4;j++){
      int o = ob*4 + j;
      float v = red[0][j][tid]+red[1][j][tid]+red[2][j][tid]+red[3][j][tid];
      tp[((size_t)b*256+o)*64 + tid] = v + b2[o];
    }
  }
}

// ---------------------------------------------------------------- wa->ew
// ew[b,o,t,s] = exp(sum_i w3[o,i]*relu(...) + b3[o])
__global__ __launch_bounds__(256) void k_wa(
    const int* __restrict__ fi, const float* __restrict__ w1,
    const float* __restrict__ b1, const float* __restrict__ tp,
    const float* __restrict__ w3, const float* __restrict__ b3,
    float* __restrict__ ew)
{
  int blk = blockIdx.x;       // ((b*64 + t)*4 + ob)
  int ob = blk & 3; int bt = blk >> 2;
  int b = bt >> 6, t = bt & 63;
  __shared__ float l0[64], l1[64], l2[64];
  __shared__ float E[128*64]; // [i][s^(i&31)]
  int tid = threadIdx.x;
  if (tid < 64){
    int rel = fi[b*64+tid] - fi[b*64+t];
    float r0 = rel>0 ? (float)rel   : 0.f;
    float r1 = rel<0 ? (float)(-rel): 0.f;
    l0[tid] = log1pf(r0);
    l1[tid] = log1pf(r1);
    l2[tid] = (rel==0) ? 0.6931471805599453f : 0.f;
  }
  int s  = tid & 63;
  int oq = __builtin_amdgcn_readfirstlane(tid>>6);
  int obase = ob*64 + oq*16;
  float acc[16];
  #pragma unroll
  for (int j=0;j<16;j++) acc[j]=0.f;
  int il  = tid >> 1;
  int sh0 = (tid & 1) * 32;
  __syncthreads();
  for (int ch=0; ch<2; ch++){
    int i = ch*128 + il;
    float wv0 = w1[i*3], wv1 = w1[i*3+1], wv2 = w1[i*3+2];
    float bb  = b1[i] + tp[((size_t)b*256 + i)*64 + t];
    #pragma unroll
    for (int k=0;k<32;k++){
      int ss = sh0 + k;
      float e = fmaf(wv0,l0[ss], fmaf(wv1,l1[ss], fmaf(wv2,l2[ss], bb)));
      E[il*64 + (ss ^ (il & 31))] = fmaxf(e, 0.f);
    }
    __syncthreads();
    const float* w3r = w3 + (size_t)obase*256 + ch*128;
    #pragma unroll 2
    for (int ii=0; ii<128; ii++){
      float ev = E[ii*64 + (s ^ (ii & 31))];
      #pragma unroll
      for (int j=0;j<16;j++) acc[j] = fmaf(w3r[(size_t)j*256 + ii], ev, acc[j]);
    }
    __syncthreads();
  }
  float* op = ew + (size_t)(b*256 + obase)*4096 + t*64 + s;
  #pragma unroll
  for (int j=0;j<16;j++) op[(size_t)j*4096] = __expf(acc[j] + b3[obase+j]);
}

// ---------------------------------------------------------------- softmax+PV
// hv_t[n,t,c] (bf16) = sum_s es[n,c%8-head,t,s]*ew[b,c,t,s]*v[n,c,s] / sum_s es*ew
__global__ __launch_bounds__(256) void k_attn(
    const float* __restrict__ es, const float* __restrict__ ew,
    const float* __restrict__ qkv, const float* __restrict__ amask,
    ushort* __restrict__ hv_t)
{
  int blk = blockIdx.x;  // (((b*8 + h)*8 + dq)*8 + cs)
  int cs = blk & 7; blk >>= 3;
  int dq = blk & 7; blk >>= 3;
  int hh = blk & 7; int b = blk >> 3;
  int tid = threadIdx.x;
  int t  = tid & 63;
  int dj = __builtin_amdgcn_readfirstlane(tid >> 6);
  int n  = b*D_ + dq*4 + dj;
  __shared__ float ml[64];
  __shared__ float4 ewl[64][16];   // [t][k^(t&15)] swizzled
  __shared__ float4 vl4[4][16];
  if (tid < 64) ml[tid] = amask[b*64 + tid];
  __syncthreads();
  float4 esr[16];
  const float4* sp = (const float4*)(es + ((size_t)(n*8 + hh))*4096 + (size_t)t*64);
  #pragma unroll
  for (int k=0;k<16;k++){
    float4 v4 = sp[k];
    v4.x = ml[4*k+0] > 0.f ? v4.x : 0.f;
    v4.y = ml[4*k+1] > 0.f ? v4.y : 0.f;
    v4.z = ml[4*k+2] > 0.f ? v4.z : 0.f;
    v4.w = ml[4*k+3] > 0.f ? v4.w : 0.f;
    esr[k] = v4;
  }
  for (int ci=0; ci<4; ci++){
    int c = (cs*4 + ci)*8 + hh;        // c % 8 == hh
    __syncthreads();
    const float4* wap = (const float4*)(ew + ((size_t)(b*256 + c))*4096);
    #pragma unroll
    for (int i=0;i<4;i++){
      int f = tid + 256*i;
      int tf = f >> 4, kf = f & 15;
      ewl[tf][kf ^ (tf & 15)] = wap[f];
    }
    if (tid < 64){
      int d = tid >> 4, k = tid & 15;
      vl4[d][k] = *(const float4*)(qkv + ((size_t)(b*D_ + dq*4 + d)*768 + 512 + c)*64 + 4*k);
    }
    __syncthreads();
    float sum = 0.f;
    float ax=0.f, ay=0.f, az=0.f, aw=0.f;
    #pragma unroll
    for (int k=0;k<16;k++){
      float4 e4 = esr[k];
      float4 w4 = ewl[t][k ^ (t & 15)];
      float4 v4 = vl4[dj][k];
      float px = e4.x*w4.x, py = e4.y*w4.y, pz = e4.z*w4.z, pw = e4.w*w4.w;
      sum += px+py+pz+pw;
      ax = fmaf(px, v4.x, ax);
      ay = fmaf(py, v4.y, ay);
      az = fmaf(pz, v4.z, az);
      aw = fmaf(pw, v4.w, aw);
    }
    float acc = (ax+ay)+(az+aw);
    hv_t[((size_t)n*64 + t)*256 + c] = f2bf(acc / sum);
  }
}

extern "C" void kernel_launch(void* const* d_in, const int* in_sizes, int n_in,
                              void* d_out, int out_size, void* d_ws, size_t ws_size,
                              hipStream_t stream) {
  const float* x     = (const float*)d_in[0];
  const float* temb  = (const float*)d_in[1];
  const int*   fi    = (const int*)  d_in[2];
  const float* amask = (const float*)d_in[3];
  const float* nsc   = (const float*)d_in[4];
  const float* nbi   = (const float*)d_in[5];
  const float* w_qkv = (const float*)d_in[6];
  const float* b_qkv = (const float*)d_in[7];
  const float* w1    = (const float*)d_in[8];
  const float* b1    = (const float*)d_in[9];
  const float* w2    = (const float*)d_in[10];
  const float* b2    = (const float*)d_in[11];
  const float* w3    = (const float*)d_in[12];
  const float* b3    = (const float*)d_in[13];
  const float* wp    = (const float*)d_in[14];
  const float* bp    = (const float*)d_in[15];
  float* out = (float*)d_out;
  float* ws  = (float*)d_ws;

  float*  qkvb = ws;                          // 3,145,728 f
  float*  esb  = qkvb + 3145728;              // 2,097,152 f
  float*  tpb  = esb  + 2097152;              //    32,768 f
  float*  ewb  = tpb  + 32768;                // 2,097,152 f
  ushort* htb  = (ushort*)(ewb + 2097152);    // 1,048,576 us
  ushort* hvb  = htb + 1048576;               // 1,048,576 us
  ushort* wqb  = hvb + 1048576;               //   196,608 us
  ushort* wpb  = wqb + 196608;                //    65,536 us

  k_castw    <<<192, 256, 0, stream>>>(w_qkv, wqb, 49152);
  k_castw    <<<64,  256, 0, stream>>>(wp,    wpb, 16384);
  k_groupnorm<<<N_*32, 256, 0, stream>>>(x, nsc, nbi, htb);
  k_mm       <<<N_*12, 256, 0, stream>>>(wqb, htb, b_qkv, nullptr, qkvb, 12, 768);
  k_scores   <<<N_*8,  256, 0, stream>>>(qkvb, esb);
  k_tproj    <<<B_*64, 256, 0, stream>>>(temb, w2, b2, tpb);
  k_wa       <<<B_*T_*4, 256, 0, stream>>>(fi, w1, b1, tpb, w3, b3, ewb);
  k_attn     <<<B_*H_*8*8, 256, 0, stream>>>(esb, ewb, qkvb, amask, hvb);
  k_mm       <<<N_*4,  256, 0, stream>>>(wpb, hvb, bp, x, out, 4, 256);
}

// Round 4
// 101.869 us; speedup vs baseline: 3.1376x; 1.2244x over previous
//
#include <hip/hip_runtime.h>

#define B_ 2
#define D_ 32
#define C_ 256
#define T_ 64
#define TE_ 1024
#define H_ 8
#define N_ 64   // B_*D_

typedef __attribute__((ext_vector_type(8))) short bf16x8;
typedef __attribute__((ext_vector_type(8))) unsigned short u16x8;
typedef __attribute__((ext_vector_type(4))) float f32x4;

__device__ inline ushort f2bf(float x){
  unsigned u = __float_as_uint(x);
  unsigned r = u + 0x7FFFu + ((u>>16)&1u);
  return (ushort)(r>>16);
}

// ---------------------------------------------------------------- weight cast
__global__ __launch_bounds__(256) void k_castw(
    const float* __restrict__ src, ushort* __restrict__ dst, int n4)
{
  int i = blockIdx.x*256 + threadIdx.x;
  if (i < n4){
    float4 v = ((const float4*)src)[i];
    ushort4 o; o.x=f2bf(v.x); o.y=f2bf(v.y); o.z=f2bf(v.z); o.w=f2bf(v.w);
    ((ushort4*)dst)[i] = o;
  }
}

// ---------------------------------------------------------------- group norm
// x (N,256,64) -> ht bf16 [n][t][c] (transposed for MFMA B-operand).
__global__ __launch_bounds__(256) void k_groupnorm(
    const float* __restrict__ x, const float* __restrict__ scale,
    const float* __restrict__ bias, ushort* __restrict__ ht)
{
  int blk = blockIdx.x;           // n*32 + g
  int n = blk >> 5, g = blk & 31;
  const float* xp = x + ((size_t)n*C_ + g*8) * T_;
  int tid = threadIdx.x;
  float v0 = xp[tid], v1 = xp[tid+256];
  float s = v0+v1, ss = v0*v0 + v1*v1;
  #pragma unroll
  for (int off=32; off; off>>=1) { s += __shfl_down(s,off); ss += __shfl_down(ss,off); }
  __shared__ float red[10];
  int wid = tid>>6, lane = tid&63;
  if (lane==0){ red[wid]=s; red[4+wid]=ss; }
  __syncthreads();
  if (tid==0){
    float a  = red[0]+red[1]+red[2]+red[3];
    float b2 = red[4]+red[5]+red[6]+red[7];
    float mean = a*(1.f/512.f);
    float var  = b2*(1.f/512.f) - mean*mean;
    red[8]=mean; red[9]=rsqrtf(var + 1e-5f);
  }
  __syncthreads();
  float mean = red[8], inv = red[9];
  int t = tid & 63;
  int c0 = g*8 + (tid>>6), c1 = c0 + 4;
  size_t rowb = ((size_t)n*T_ + t)*C_;
  ht[rowb + c0] = f2bf((v0-mean)*inv*scale[c0] + bias[c0]);
  ht[rowb + c1] = f2bf((v1-mean)*inv*scale[c1] + bias[c1]);
}

// ---------------------------------------------------------------- MFMA GEMM
// Out[n,o,t] = sum_c Wb[o,c]*Inb[n,t,c] + bias[o] (+resid), K=256, bf16 MFMA.
__global__ __launch_bounds__(256) void k_mm(
    const ushort* __restrict__ Wb, const ushort* __restrict__ Inb,
    const float* __restrict__ bias, const float* __restrict__ resid,
    float* __restrict__ Out, int oblocks, int Ototal)
{
  int blk = blockIdx.x;
  int n = blk / oblocks, ob = blk - n*oblocks;
  int tid = threadIdx.x;
  int lane = tid & 63, w = tid >> 6;
  int o0 = ob*64 + w*16;
  int r = lane & 15, kg = lane >> 4;
  const ushort* wp = Wb + (size_t)(o0 + r)*256 + kg*8;
  const ushort* ip = Inb + ((size_t)n*64 + r)*256 + kg*8;
  f32x4 acc[4];
  #pragma unroll
  for (int j=0;j<4;j++) acc[j] = (f32x4){0.f,0.f,0.f,0.f};
  #pragma unroll
  for (int ks = 0; ks < 8; ks++) {
    bf16x8 a = *(const bf16x8*)(wp + ks*32);
    #pragma unroll
    for (int j = 0; j < 4; j++) {
      bf16x8 b = *(const bf16x8*)(ip + (size_t)j*16*256 + ks*32);
      acc[j] = __builtin_amdgcn_mfma_f32_16x16x32_bf16(a, b, acc[j], 0, 0, 0);
    }
  }
  #pragma unroll
  for (int j = 0; j < 4; j++) {
    #pragma unroll
    for (int rr = 0; rr < 4; rr++) {
      int o = o0 + kg*4 + rr;
      size_t idx = ((size_t)n*Ototal + o)*64 + j*16 + r;
      float v = acc[j][rr] + bias[o];
      if (resid) v += resid[idx];
      Out[idx] = v;
    }
  }
}

// ---------------------------------------------------------------- scores->es
// es[n,h,t,s] = exp((1/sqrt(32)) * sum_cq q[cq,t]*k[cq,s])
__global__ __launch_bounds__(256) void k_scores(
    const float* __restrict__ qkv, float* __restrict__ es)
{
  int blk = blockIdx.x;          // n*8 + h
  int n = blk >> 3, hh = blk & 7;
  __shared__ float qs[32*64], ks[32*64];
  int tid = threadIdx.x;
  const float* base = qkv + (size_t)n*(768*64);
  for (int i=tid; i<2048; i+=256){
    int cq = i>>6, tt = i&63;
    qs[i] = base[(cq*8+hh)*64 + tt];
    ks[i] = base[(256 + cq*8+hh)*64 + tt];
  }
  __syncthreads();
  int s  = tid & 63;
  int t4 = __builtin_amdgcn_readfirstlane(tid>>6);
  float acc[16];
  #pragma unroll
  for (int j=0;j<16;j++) acc[j]=0.f;
  for (int cq=0;cq<32;cq++){
    float kv = ks[cq*64+s];
    #pragma unroll
    for (int j=0;j<16;j++) acc[j] = fmaf(qs[cq*64 + t4*16 + j], kv, acc[j]);
  }
  float* op = es + (size_t)blk*4096;
  const float sc = 0.17677669529663687f; // 1/sqrt(32)
  #pragma unroll
  for (int j=0;j<16;j++) op[(t4*16+j)*64 + s] = __expf(acc[j]*sc);
}

// ---------------------------------------------------------------- temb proj
__global__ __launch_bounds__(256) void k_tproj(
    const float* __restrict__ temb, const float* __restrict__ w2,
    const float* __restrict__ b2, float* __restrict__ tp)
{
  __shared__ float w2s[4*1024];
  __shared__ float red[4][4][64];
  int blk = blockIdx.x;
  int b = blk >> 6, ob = blk & 63;
  int tid = threadIdx.x;
  const float* w2p = w2 + (size_t)ob*4*1024;
  #pragma unroll
  for (int r = 0; r < 16; r++) w2s[r*256 + tid] = w2p[r*256 + tid];
  __syncthreads();
  int t = tid & 63, eq = tid >> 6;
  const float* tep = temb + ((size_t)b*1024 + eq*256)*64 + t;
  const float* wq  = w2s + eq*256;
  float acc[4] = {0.f,0.f,0.f,0.f};
  #pragma unroll 4
  for (int i = 0; i < 256; i += 4) {
    float tv0 = tep[(i+0)*64];
    float tv1 = tep[(i+1)*64];
    float tv2 = tep[(i+2)*64];
    float tv3 = tep[(i+3)*64];
    #pragma unroll
    for (int j = 0; j < 4; j++) {
      float4 w4 = *(const float4*)&wq[j*1024 + i];
      acc[j] = fmaf(w4.x, tv0, acc[j]);
      acc[j] = fmaf(w4.y, tv1, acc[j]);
      acc[j] = fmaf(w4.z, tv2, acc[j]);
      acc[j] = fmaf(w4.w, tv3, acc[j]);
    }
  }
  #pragma unroll
  for (int j=0;j<4;j++) red[eq][j][t] = acc[j];
  __syncthreads();
  if (tid < 64) {
    #pragma unroll
    for (int j=0;j<4;j++){
      int o = ob*4 + j;
      float v = red[0][j][tid]+red[1][j][tid]+red[2][j][tid]+red[3][j][tid];
      tp[((size_t)b*256+o)*64 + tid] = v + b2[o];
    }
  }
}

// ---------------------------------------------------------------- wa (MFMA)
// ew[b,o,t,s] = exp(sum_i w3[o,i]*relu(w1[i]·l(s)+b1[i]+tp[b,i,t]) + b3[o])
// block = (b, t, o-half). E[s][i] bf16 in LDS, chunk-XOR swizzled; bf16 MFMA.
__global__ __launch_bounds__(256) void k_wamm(
    const int* __restrict__ fi, const float* __restrict__ w1,
    const float* __restrict__ b1, const float* __restrict__ tp,
    const ushort* __restrict__ w3b, const float* __restrict__ b3,
    float* __restrict__ ew)
{
  int blk = blockIdx.x;            // ((b*64 + t)*2 + oh)
  int oh = blk & 1; int bt = blk >> 1;
  int b = bt >> 6, t = bt & 63;
  __shared__ float l0[64], l1[64], l2[64];
  __shared__ ushort Ebuf[64*256];  // 32 KB, chunk i8^(s&31) swizzled
  int tid = threadIdx.x;
  if (tid < 64){
    int rel = fi[b*64+tid] - fi[b*64+t];
    float r0 = rel>0 ? (float)rel   : 0.f;
    float r1 = rel<0 ? (float)(-rel): 0.f;
    l0[tid] = log1pf(r0);
    l1[tid] = log1pf(r1);
    l2[tid] = (rel==0) ? 0.6931471805599453f : 0.f;
  }
  __syncthreads();
  int s = tid & 63;
  int iq = __builtin_amdgcn_readfirstlane(tid >> 6);
  float L0 = l0[s], L1 = l1[s], L2 = l2[s];
  #pragma unroll
  for (int c8 = 0; c8 < 8; c8++){
    int chunk = iq*8 + c8;         // i8 index 0..31 (wave-uniform)
    int ibase = chunk*8;
    u16x8 pack;
    #pragma unroll
    for (int e = 0; e < 8; e++){
      int i = ibase + e;
      float bb = b1[i] + tp[((size_t)b*256 + i)*64 + t];   // wave-uniform s_loads
      float ev = fmaf(w1[i*3], L0, fmaf(w1[i*3+1], L1, fmaf(w1[i*3+2], L2, bb)));
      pack[e] = f2bf(fmaxf(ev, 0.f));
    }
    int csw = chunk ^ (s & 31);
    *(u16x8*)&Ebuf[s*256 + csw*8] = pack;
  }
  __syncthreads();
  int lane = tid & 63, w = tid >> 6;
  int r = lane & 15, kg = lane >> 4;
  int o0 = oh*128 + w*32;
  f32x4 acc[2][4];
  #pragma unroll
  for (int m=0;m<2;m++)
    #pragma unroll
    for (int j=0;j<4;j++) acc[m][j] = (f32x4){0.f,0.f,0.f,0.f};
  #pragma unroll
  for (int ks = 0; ks < 8; ks++){
    bf16x8 a0 = *(const bf16x8*)(w3b + (size_t)(o0 +      r)*256 + kg*8 + ks*32);
    bf16x8 a1 = *(const bf16x8*)(w3b + (size_t)(o0 + 16 + r)*256 + kg*8 + ks*32);
    #pragma unroll
    for (int j=0;j<4;j++){
      int srow = j*16 + r;
      int chunk = (kg + ks*4) ^ (srow & 31);
      bf16x8 bfr = *(const bf16x8*)&Ebuf[srow*256 + chunk*8];
      acc[0][j] = __builtin_amdgcn_mfma_f32_16x16x32_bf16(a0, bfr, acc[0][j], 0, 0, 0);
      acc[1][j] = __builtin_amdgcn_mfma_f32_16x16x32_bf16(a1, bfr, acc[1][j], 0, 0, 0);
    }
  }
  #pragma unroll
  for (int m=0;m<2;m++){
    #pragma unroll
    for (int j=0;j<4;j++){
      #pragma unroll
      for (int rr=0;rr<4;rr++){
        int o = o0 + m*16 + kg*4 + rr;
        int scol = j*16 + r;
        ew[((size_t)(b*256+o))*4096 + t*64 + scol] = __expf(acc[m][j][rr] + b3[o]);
      }
    }
  }
}

// ---------------------------------------------------------------- softmax+PV
// hv_t[n,t,c] (bf16) = sum_s es[n,h(c),t,s]*ew[b,c,t,s]*v[n,c,s] / sum es*ew
__global__ __launch_bounds__(256) void k_attn(
    const float* __restrict__ es, const float* __restrict__ ew,
    const float* __restrict__ qkv, const float* __restrict__ amask,
    ushort* __restrict__ hv_t)
{
  int blk = blockIdx.x;  // (((b*8 + h)*8 + dq)*8 + cs)
  int cs = blk & 7; blk >>= 3;
  int dq = blk & 7; blk >>= 3;
  int hh = blk & 7; int b = blk >> 3;
  int tid = threadIdx.x;
  int t  = tid & 63;
  int dj = __builtin_amdgcn_readfirstlane(tid >> 6);
  int n  = b*D_ + dq*4 + dj;
  __shared__ float ml[64];
  __shared__ float4 ewl[64][16];   // [t][k^(t&15)] swizzled
  __shared__ float4 vl4[4][16];
  if (tid < 64) ml[tid] = amask[b*64 + tid];
  __syncthreads();
  float4 esr[16];
  const float4* sp = (const float4*)(es + ((size_t)(n*8 + hh))*4096 + (size_t)t*64);
  #pragma unroll
  for (int k=0;k<16;k++){
    float4 v4 = sp[k];
    v4.x = ml[4*k+0] > 0.f ? v4.x : 0.f;
    v4.y = ml[4*k+1] > 0.f ? v4.y : 0.f;
    v4.z = ml[4*k+2] > 0.f ? v4.z : 0.f;
    v4.w = ml[4*k+3] > 0.f ? v4.w : 0.f;
    esr[k] = v4;
  }
  for (int ci=0; ci<4; ci++){
    int c = (cs*4 + ci)*8 + hh;        // c % 8 == hh
    __syncthreads();
    const float4* wap = (const float4*)(ew + ((size_t)(b*256 + c))*4096);
    #pragma unroll
    for (int i=0;i<4;i++){
      int f = tid + 256*i;
      int tf = f >> 4, kf = f & 15;
      ewl[tf][kf ^ (tf & 15)] = wap[f];
    }
    if (tid < 64){
      int d = tid >> 4, k = tid & 15;
      vl4[d][k] = *(const float4*)(qkv + ((size_t)(b*D_ + dq*4 + d)*768 + 512 + c)*64 + 4*k);
    }
    __syncthreads();
    float sum = 0.f;
    float ax=0.f, ay=0.f, az=0.f, aw=0.f;
    #pragma unroll
    for (int k=0;k<16;k++){
      float4 e4 = esr[k];
      float4 w4 = ewl[t][k ^ (t & 15)];
      float4 v4 = vl4[dj][k];
      float px = e4.x*w4.x, py = e4.y*w4.y, pz = e4.z*w4.z, pw = e4.w*w4.w;
      sum += px+py+pz+pw;
      ax = fmaf(px, v4.x, ax);
      ay = fmaf(py, v4.y, ay);
      az = fmaf(pz, v4.z, az);
      aw = fmaf(pw, v4.w, aw);
    }
    float acc = (ax+ay)+(az+aw);
    hv_t[((size_t)n*64 + t)*256 + c] = f2bf(acc / sum);
  }
}

extern "C" void kernel_launch(void* const* d_in, const int* in_sizes, int n_in,
                              void* d_out, int out_size, void* d_ws, size_t ws_size,
                              hipStream_t stream) {
  const float* x     = (const float*)d_in[0];
  const float* temb  = (const float*)d_in[1];
  const int*   fi    = (const int*)  d_in[2];
  const float* amask = (const float*)d_in[3];
  const float* nsc   = (const float*)d_in[4];
  const float* nbi   = (const float*)d_in[5];
  const float* w_qkv = (const float*)d_in[6];
  const float* b_qkv = (const float*)d_in[7];
  const float* w1    = (const float*)d_in[8];
  const float* b1    = (const float*)d_in[9];
  const float* w2    = (const float*)d_in[10];
  const float* b2    = (const float*)d_in[11];
  const float* w3    = (const float*)d_in[12];
  const float* b3    = (const float*)d_in[13];
  const float* wp    = (const float*)d_in[14];
  const float* bp    = (const float*)d_in[15];
  float* out = (float*)d_out;
  float* ws  = (float*)d_ws;

  float*  qkvb = ws;                          // 3,145,728 f
  float*  esb  = qkvb + 3145728;              // 2,097,152 f
  float*  tpb  = esb  + 2097152;              //    32,768 f
  float*  ewb  = tpb  + 32768;                // 2,097,152 f
  ushort* htb  = (ushort*)(ewb + 2097152);    // 1,048,576 us
  ushort* hvb  = htb + 1048576;               // 1,048,576 us
  ushort* wqb  = hvb + 1048576;               //   196,608 us
  ushort* wpb  = wqb + 196608;                //    65,536 us
  ushort* w3b  = wpb + 65536;                 //    65,536 us

  k_castw    <<<192, 256, 0, stream>>>(w_qkv, wqb, 49152);
  k_castw    <<<64,  256, 0, stream>>>(wp,    wpb, 16384);
  k_castw    <<<64,  256, 0, stream>>>(w3,    w3b, 16384);
  k_groupnorm<<<N_*32, 256, 0, stream>>>(x, nsc, nbi, htb);
  k_mm       <<<N_*12, 256, 0, stream>>>(wqb, htb, b_qkv, nullptr, qkvb, 12, 768);
  k_scores   <<<N_*8,  256, 0, stream>>>(qkvb, esb);
  k_tproj    <<<B_*64, 256, 0, stream>>>(temb, w2, b2, tpb);
  k_wamm     <<<B_*T_*2, 256, 0, stream>>>(fi, w1, b1, tpb, w3b, b3, ewb);
  k_attn     <<<B_*H_*8*8, 256, 0, stream>>>(esb, ewb, qkvb, amask, hvb);
  k_mm       <<<N_*4,  256, 0, stream>>>(wpb, hvb, bp, x, out, 4, 256);
}

// Round 5
// 96.052 us; speedup vs baseline: 3.3277x; 1.0606x over previous
//
#include <hip/hip_runtime.h>

#define B_ 2
#define D_ 32
#define C_ 256
#define T_ 64
#define TE_ 1024
#define H_ 8
#define N_ 64   // B_*D_

typedef __attribute__((ext_vector_type(8))) short bf16x8;
typedef __attribute__((ext_vector_type(8))) unsigned short u16x8;
typedef __attribute__((ext_vector_type(4))) float f32x4;

__device__ inline ushort f2bf(float x){
  unsigned u = __float_as_uint(x);
  unsigned r = u + 0x7FFFu + ((u>>16)&1u);
  return (ushort)(r>>16);
}

// ---------------------------------------------------------------- prep
// blocks [0,192): cast w_qkv | [192,256): cast wp | [256,320): cast w3
// [320,2368): groupnorm | [2368,2496): tproj
__global__ __launch_bounds__(256) void k_prep(
    const float* __restrict__ w_qkv, const float* __restrict__ wp,
    const float* __restrict__ w3,
    ushort* __restrict__ wqb, ushort* __restrict__ wpb, ushort* __restrict__ w3b,
    const float* __restrict__ x, const float* __restrict__ nsc,
    const float* __restrict__ nbi, ushort* __restrict__ ht,
    const float* __restrict__ temb, const float* __restrict__ w2,
    const float* __restrict__ b2, float* __restrict__ tp)
{
  __shared__ float smem[5120];   // tproj: w2s[4096]+red[1024]; groupnorm: red[10]
  int blk = blockIdx.x;
  int tid = threadIdx.x;
  if (blk < 320) {
    const float* src; ushort* dst; int n4, i0;
    if (blk < 192)      { src = w_qkv; dst = wqb; n4 = 49152; i0 = blk; }
    else if (blk < 256) { src = wp;    dst = wpb; n4 = 16384; i0 = blk-192; }
    else                { src = w3;    dst = w3b; n4 = 16384; i0 = blk-256; }
    int i = i0*256 + tid;
    if (i < n4){
      float4 v = ((const float4*)src)[i];
      ushort4 o; o.x=f2bf(v.x); o.y=f2bf(v.y); o.z=f2bf(v.z); o.w=f2bf(v.w);
      ((ushort4*)dst)[i] = o;
    }
    return;
  }
  if (blk < 2368) {
    // -------- group norm: x (N,256,64) -> ht bf16 [n][t][c]
    int b2k = blk - 320;
    int n = b2k >> 5, g = b2k & 31;
    const float* xp = x + ((size_t)n*C_ + g*8) * T_;
    float v0 = xp[tid], v1 = xp[tid+256];
    float s = v0+v1, ss = v0*v0 + v1*v1;
    #pragma unroll
    for (int off=32; off; off>>=1) { s += __shfl_down(s,off); ss += __shfl_down(ss,off); }
    float* red = smem;
    int wid = tid>>6, lane = tid&63;
    if (lane==0){ red[wid]=s; red[4+wid]=ss; }
    __syncthreads();
    if (tid==0){
      float a  = red[0]+red[1]+red[2]+red[3];
      float bb = red[4]+red[5]+red[6]+red[7];
      float mean = a*(1.f/512.f);
      float var  = bb*(1.f/512.f) - mean*mean;
      red[8]=mean; red[9]=rsqrtf(var + 1e-5f);
    }
    __syncthreads();
    float mean = red[8], inv = red[9];
    int t = tid & 63;
    int c0 = g*8 + (tid>>6), c1 = c0 + 4;
    size_t rowb = ((size_t)n*T_ + t)*C_;
    ht[rowb + c0] = f2bf((v0-mean)*inv*nsc[c0] + nbi[c0]);
    ht[rowb + c1] = f2bf((v1-mean)*inv*nsc[c1] + nbi[c1]);
    return;
  }
  // -------- tproj: tp[b,o,t] = sum_e temb[b,e,t]*w2[o,e] + b2[o]
  {
    int b3k = blk - 2368;
    int b = b3k >> 6, ob = b3k & 63;
    float* w2s = smem;                       // 4*1024
    float* red = smem + 4096;                // [4][4][64]
    const float* w2p = w2 + (size_t)ob*4*1024;
    #pragma unroll
    for (int r = 0; r < 16; r++) w2s[r*256 + tid] = w2p[r*256 + tid];
    __syncthreads();
    int t = tid & 63, eq = tid >> 6;
    const float* tep = temb + ((size_t)b*1024 + eq*256)*64 + t;
    const float* wq  = w2s + eq*256;
    float acc[4] = {0.f,0.f,0.f,0.f};
    #pragma unroll 4
    for (int i = 0; i < 256; i += 4) {
      float tv0 = tep[(i+0)*64];
      float tv1 = tep[(i+1)*64];
      float tv2 = tep[(i+2)*64];
      float tv3 = tep[(i+3)*64];
      #pragma unroll
      for (int j = 0; j < 4; j++) {
        float4 w4 = *(const float4*)&wq[j*1024 + i];
        acc[j] = fmaf(w4.x, tv0, acc[j]);
        acc[j] = fmaf(w4.y, tv1, acc[j]);
        acc[j] = fmaf(w4.z, tv2, acc[j]);
        acc[j] = fmaf(w4.w, tv3, acc[j]);
      }
    }
    #pragma unroll
    for (int j=0;j<4;j++) red[(eq*4+j)*64 + t] = acc[j];
    __syncthreads();
    if (tid < 64) {
      #pragma unroll
      for (int j=0;j<4;j++){
        int o = ob*4 + j;
        float v = red[j*64+tid]+red[(4+j)*64+tid]+red[(8+j)*64+tid]+red[(12+j)*64+tid];
        tp[((size_t)b*256+o)*64 + tid] = v + b2[o];
      }
    }
  }
}

// ---------------------------------------------------------------- MFMA GEMM
// Out[n,o,t] = sum_c Wb[o,c]*Inb[n,t,c] + bias[o] (+resid), K=256, bf16 MFMA.
__global__ __launch_bounds__(256) void k_mm(
    const ushort* __restrict__ Wb, const ushort* __restrict__ Inb,
    const float* __restrict__ bias, const float* __restrict__ resid,
    float* __restrict__ Out, int oblocks, int Ototal)
{
  int blk = blockIdx.x;
  int n = blk / oblocks, ob = blk - n*oblocks;
  int tid = threadIdx.x;
  int lane = tid & 63, w = tid >> 6;
  int o0 = ob*64 + w*16;
  int r = lane & 15, kg = lane >> 4;
  const ushort* wp = Wb + (size_t)(o0 + r)*256 + kg*8;
  const ushort* ip = Inb + ((size_t)n*64 + r)*256 + kg*8;
  f32x4 acc[4];
  #pragma unroll
  for (int j=0;j<4;j++) acc[j] = (f32x4){0.f,0.f,0.f,0.f};
  #pragma unroll
  for (int ks = 0; ks < 8; ks++) {
    bf16x8 a = *(const bf16x8*)(wp + ks*32);
    #pragma unroll
    for (int j = 0; j < 4; j++) {
      bf16x8 b = *(const bf16x8*)(ip + (size_t)j*16*256 + ks*32);
      acc[j] = __builtin_amdgcn_mfma_f32_16x16x32_bf16(a, b, acc[j], 0, 0, 0);
    }
  }
  #pragma unroll
  for (int j = 0; j < 4; j++) {
    #pragma unroll
    for (int rr = 0; rr < 4; rr++) {
      int o = o0 + kg*4 + rr;
      size_t idx = ((size_t)n*Ototal + o)*64 + j*16 + r;
      float v = acc[j][rr] + bias[o];
      if (resid) v += resid[idx];
      Out[idx] = v;
    }
  }
}

// ---------------------------------------------------------------- scores+wa
// blocks [0,512): es[n,h,t,s] = exp(qk/sqrt(32));  [512,768): wamm -> ew
__global__ __launch_bounds__(256) void k_sw(
    const float* __restrict__ qkv, float* __restrict__ es,
    const int* __restrict__ fi, const float* __restrict__ w1,
    const float* __restrict__ b1, const float* __restrict__ tp,
    const ushort* __restrict__ w3b, const float* __restrict__ b3,
    float* __restrict__ ew)
{
  __shared__ char smem[33536];
  int blk = blockIdx.x;
  int tid = threadIdx.x;
  if (blk < 512) {
    // -------- scores -> es
    int n = blk >> 3, hh = blk & 7;
    float* qs = (float*)smem;          // 2048
    float* ks = qs + 2048;             // 2048
    const float* base = qkv + (size_t)n*(768*64);
    for (int i=tid; i<2048; i+=256){
      int cq = i>>6, tt = i&63;
      qs[i] = base[(cq*8+hh)*64 + tt];
      ks[i] = base[(256 + cq*8+hh)*64 + tt];
    }
    __syncthreads();
    int s  = tid & 63;
    int t4 = __builtin_amdgcn_readfirstlane(tid>>6);
    float acc[16];
    #pragma unroll
    for (int j=0;j<16;j++) acc[j]=0.f;
    for (int cq=0;cq<32;cq++){
      float kv = ks[cq*64+s];
      #pragma unroll
      for (int j=0;j<16;j++) acc[j] = fmaf(qs[cq*64 + t4*16 + j], kv, acc[j]);
    }
    float* op = es + (size_t)blk*4096;
    const float sc = 0.17677669529663687f; // 1/sqrt(32)
    #pragma unroll
    for (int j=0;j<16;j++) op[(t4*16+j)*64 + s] = __expf(acc[j]*sc);
    return;
  }
  // -------- wamm -> ew
  {
    int blk2 = blk - 512;              // ((b*64 + t)*2 + oh)
    int oh = blk2 & 1; int bt = blk2 >> 1;
    int b = bt >> 6, t = bt & 63;
    float* l0 = (float*)smem;          // 64
    float* l1 = l0 + 64;
    float* l2 = l1 + 64;
    ushort* Ebuf = (ushort*)(smem + 768);   // 64*256 ushort, chunk-swizzled
    if (tid < 64){
      int rel = fi[b*64+tid] - fi[b*64+t];
      float r0 = rel>0 ? (float)rel   : 0.f;
      float r1 = rel<0 ? (float)(-rel): 0.f;
      l0[tid] = log1pf(r0);
      l1[tid] = log1pf(r1);
      l2[tid] = (rel==0) ? 0.6931471805599453f : 0.f;
    }
    __syncthreads();
    int s = tid & 63;
    int iq = __builtin_amdgcn_readfirstlane(tid >> 6);
    float L0 = l0[s], L1 = l1[s], L2 = l2[s];
    #pragma unroll
    for (int c8 = 0; c8 < 8; c8++){
      int chunk = iq*8 + c8;
      int ibase = chunk*8;
      u16x8 pack;
      #pragma unroll
      for (int e = 0; e < 8; e++){
        int i = ibase + e;
        float bb = b1[i] + tp[((size_t)b*256 + i)*64 + t];
        float evv = fmaf(w1[i*3], L0, fmaf(w1[i*3+1], L1, fmaf(w1[i*3+2], L2, bb)));
        pack[e] = f2bf(fmaxf(evv, 0.f));
      }
      int csw = chunk ^ (s & 31);
      *(u16x8*)&Ebuf[s*256 + csw*8] = pack;
    }
    __syncthreads();
    int lane = tid & 63, w = tid >> 6;
    int r = lane & 15, kg = lane >> 4;
    int o0 = oh*128 + w*32;
    f32x4 acc[2][4];
    #pragma unroll
    for (int m=0;m<2;m++)
      #pragma unroll
      for (int j=0;j<4;j++) acc[m][j] = (f32x4){0.f,0.f,0.f,0.f};
    #pragma unroll
    for (int ks8 = 0; ks8 < 8; ks8++){
      bf16x8 a0 = *(const bf16x8*)(w3b + (size_t)(o0 +      r)*256 + kg*8 + ks8*32);
      bf16x8 a1 = *(const bf16x8*)(w3b + (size_t)(o0 + 16 + r)*256 + kg*8 + ks8*32);
      #pragma unroll
      for (int j=0;j<4;j++){
        int srow = j*16 + r;
        int chunk = (kg + ks8*4) ^ (srow & 31);
        bf16x8 bfr = *(const bf16x8*)&Ebuf[srow*256 + chunk*8];
        acc[0][j] = __builtin_amdgcn_mfma_f32_16x16x32_bf16(a0, bfr, acc[0][j], 0, 0, 0);
        acc[1][j] = __builtin_amdgcn_mfma_f32_16x16x32_bf16(a1, bfr, acc[1][j], 0, 0, 0);
      }
    }
    #pragma unroll
    for (int m=0;m<2;m++){
      #pragma unroll
      for (int j=0;j<4;j++){
        #pragma unroll
        for (int rr=0;rr<4;rr++){
          int o = o0 + m*16 + kg*4 + rr;
          int scol = j*16 + r;
          ew[((size_t)(b*256+o))*4096 + t*64 + scol] = __expf(acc[m][j][rr] + b3[o]);
        }
      }
    }
  }
}

// ---------------------------------------------------------------- softmax+PV
// hv_t[n,t,c] (bf16) = sum_s es[n,h(c),t,s]*ew[b,c,t,s]*v[n,c,s] / sum es*ew
// Pipelined: next (ew,v) tile prefetched to regs during current compute.
__global__ __launch_bounds__(256) void k_attn(
    const float* __restrict__ es, const float* __restrict__ ew,
    const float* __restrict__ qkv, const float* __restrict__ amask,
    ushort* __restrict__ hv_t)
{
  int blk = blockIdx.x;  // (((b*8 + h)*8 + dq)*8 + cs)
  int cs = blk & 7; blk >>= 3;
  int dq = blk & 7; blk >>= 3;
  int hh = blk & 7; int b = blk >> 3;
  int tid = threadIdx.x;
  int t  = tid & 63;
  int dj = __builtin_amdgcn_readfirstlane(tid >> 6);
  int n  = b*D_ + dq*4 + dj;
  __shared__ float ml[64];
  __shared__ float4 ewl[64][16];   // [t][k^(t&15)] swizzled
  __shared__ float4 vl4[4][16];
  if (tid < 64) ml[tid] = amask[b*64 + tid];
  __syncthreads();
  float4 esr[16];
  const float4* sp = (const float4*)(es + ((size_t)(n*8 + hh))*4096 + (size_t)t*64);
  #pragma unroll
  for (int k=0;k<16;k++){
    float4 v4 = sp[k];
    v4.x = ml[4*k+0] > 0.f ? v4.x : 0.f;
    v4.y = ml[4*k+1] > 0.f ? v4.y : 0.f;
    v4.z = ml[4*k+2] > 0.f ? v4.z : 0.f;
    v4.w = ml[4*k+3] > 0.f ? v4.w : 0.f;
    esr[k] = v4;
  }
  int tf = tid >> 4, kf = tid & 15;          // ew stage coords (4 rows/pass)
  int vd = tid >> 4, vk = tid & 15;          // v stage coords (tid<64)
  float4 rew[4]; float4 rv;
  // prologue: load tiles for ci=0
  {
    int c = cs*32 + hh;
    const float4* wap = (const float4*)(ew + ((size_t)(b*256 + c))*4096);
    #pragma unroll
    for (int i=0;i<4;i++) rew[i] = wap[tid + 256*i];
    if (tid < 64)
      rv = *(const float4*)(qkv + ((size_t)(b*D_ + dq*4 + vd)*768 + 512 + c)*64 + 4*vk);
  }
  for (int ci=0; ci<4; ci++){
    __syncthreads();
    #pragma unroll
    for (int i=0;i<4;i++){
      int f = tid + 256*i;
      int tr = f >> 4, kr = f & 15;
      ewl[tr][kr ^ (tr & 15)] = rew[i];
    }
    if (tid < 64) vl4[vd][vk] = rv;
    __syncthreads();
    if (ci < 3){
      int c = (cs*4 + ci + 1)*8 + hh;
      const float4* wap = (const float4*)(ew + ((size_t)(b*256 + c))*4096);
      #pragma unroll
      for (int i=0;i<4;i++) rew[i] = wap[tid + 256*i];
      if (tid < 64)
        rv = *(const float4*)(qkv + ((size_t)(b*D_ + dq*4 + vd)*768 + 512 + c)*64 + 4*vk);
    }
    float sum = 0.f;
    float ax=0.f, ay=0.f, az=0.f, aw=0.f;
    #pragma unroll
    for (int k=0;k<16;k++){
      float4 e4 = esr[k];
      float4 w4 = ewl[t][k ^ (t & 15)];
      float4 v4 = vl4[dj][k];
      float px = e4.x*w4.x, py = e4.y*w4.y, pz = e4.z*w4.z, pw = e4.w*w4.w;
      sum += px+py+pz+pw;
      ax = fmaf(px, v4.x, ax);
      ay = fmaf(py, v4.y, ay);
      az = fmaf(pz, v4.z, az);
      aw = fmaf(pw, v4.w, aw);
    }
    float acc = (ax+ay)+(az+aw);
    int c = (cs*4 + ci)*8 + hh;
    hv_t[((size_t)n*64 + t)*256 + c] = f2bf(acc / sum);
  }
}

extern "C" void kernel_launch(void* const* d_in, const int* in_sizes, int n_in,
                              void* d_out, int out_size, void* d_ws, size_t ws_size,
                              hipStream_t stream) {
  const float* x     = (const float*)d_in[0];
  const float* temb  = (const float*)d_in[1];
  const int*   fi    = (const int*)  d_in[2];
  const float* amask = (const float*)d_in[3];
  const float* nsc   = (const float*)d_in[4];
  const float* nbi   = (const float*)d_in[5];
  const float* w_qkv = (const float*)d_in[6];
  const float* b_qkv = (const float*)d_in[7];
  const float* w1    = (const float*)d_in[8];
  const float* b1    = (const float*)d_in[9];
  const float* w2    = (const float*)d_in[10];
  const float* b2    = (const float*)d_in[11];
  const float* w3    = (const float*)d_in[12];
  const float* b3    = (const float*)d_in[13];
  const float* wp    = (const float*)d_in[14];
  const float* bp    = (const float*)d_in[15];
  float* out = (float*)d_out;
  float* ws  = (float*)d_ws;

  float*  qkvb = ws;                          // 3,145,728 f
  float*  esb  = qkvb + 3145728;              // 2,097,152 f
  float*  tpb  = esb  + 2097152;              //    32,768 f
  float*  ewb  = tpb  + 32768;                // 2,097,152 f
  ushort* htb  = (ushort*)(ewb + 2097152);    // 1,048,576 us
  ushort* hvb  = htb + 1048576;               // 1,048,576 us
  ushort* wqb  = hvb + 1048576;               //   196,608 us
  ushort* wpb  = wqb + 196608;                //    65,536 us
  ushort* w3b  = wpb + 65536;                 //    65,536 us

  k_prep <<<2496, 256, 0, stream>>>(w_qkv, wp, w3, wqb, wpb, w3b,
                                    x, nsc, nbi, htb, temb, w2, b2, tpb);
  k_mm   <<<N_*12, 256, 0, stream>>>(wqb, htb, b_qkv, nullptr, qkvb, 12, 768);
  k_sw   <<<768, 256, 0, stream>>>(qkvb, esb, fi, w1, b1, tpb, w3b, b3, ewb);
  k_attn <<<B_*H_*8*8, 256, 0, stream>>>(esb, ewb, qkvb, amask, hvb);
  k_mm   <<<N_*4,  256, 0, stream>>>(wpb, hvb, bp, x, out, 4, 256);
}

// Round 6
// 75.737 us; speedup vs baseline: 4.2203x; 1.2682x over previous
//
#include <hip/hip_runtime.h>

#define B_ 2
#define D_ 32
#define C_ 256
#define T_ 64
#define TE_ 1024
#define H_ 8
#define N_ 64   // B_*D_

typedef __attribute__((ext_vector_type(8))) short bf16x8;
typedef __attribute__((ext_vector_type(8))) unsigned short u16x8;
typedef __attribute__((ext_vector_type(4))) float f32x4;

__device__ inline ushort f2bf(float x){
  unsigned u = __float_as_uint(x);
  unsigned r = u + 0x7FFFu + ((u>>16)&1u);
  return (ushort)(r>>16);
}
__device__ inline float bf2f(ushort u){
  return __uint_as_float(((unsigned)u)<<16);
}

// ---------------------------------------------------------------- prep
// blocks [0,192): cast w_qkv | [192,256): cast wp | [256,320): cast w3
// [320,2368): groupnorm | [2368,2496): tproj
__global__ __launch_bounds__(256) void k_prep(
    const float* __restrict__ w_qkv, const float* __restrict__ wp,
    const float* __restrict__ w3,
    ushort* __restrict__ wqb, ushort* __restrict__ wpb, ushort* __restrict__ w3b,
    const float* __restrict__ x, const float* __restrict__ nsc,
    const float* __restrict__ nbi, ushort* __restrict__ ht,
    const float* __restrict__ temb, const float* __restrict__ w2,
    const float* __restrict__ b2, float* __restrict__ tp)
{
  __shared__ float smem[5120];
  int blk = blockIdx.x;
  int tid = threadIdx.x;
  if (blk < 320) {
    const float* src; ushort* dst; int n4, i0;
    if (blk < 192)      { src = w_qkv; dst = wqb; n4 = 49152; i0 = blk; }
    else if (blk < 256) { src = wp;    dst = wpb; n4 = 16384; i0 = blk-192; }
    else                { src = w3;    dst = w3b; n4 = 16384; i0 = blk-256; }
    int i = i0*256 + tid;
    if (i < n4){
      float4 v = ((const float4*)src)[i];
      ushort4 o; o.x=f2bf(v.x); o.y=f2bf(v.y); o.z=f2bf(v.z); o.w=f2bf(v.w);
      ((ushort4*)dst)[i] = o;
    }
    return;
  }
  if (blk < 2368) {
    // -------- group norm: x (N,256,64) -> ht bf16 [n][t][c]
    int b2k = blk - 320;
    int n = b2k >> 5, g = b2k & 31;
    const float* xp = x + ((size_t)n*C_ + g*8) * T_;
    float v0 = xp[tid], v1 = xp[tid+256];
    float s = v0+v1, ss = v0*v0 + v1*v1;
    #pragma unroll
    for (int off=32; off; off>>=1) { s += __shfl_down(s,off); ss += __shfl_down(ss,off); }
    float* red = smem;
    int wid = tid>>6, lane = tid&63;
    if (lane==0){ red[wid]=s; red[4+wid]=ss; }
    __syncthreads();
    if (tid==0){
      float a  = red[0]+red[1]+red[2]+red[3];
      float bb = red[4]+red[5]+red[6]+red[7];
      float mean = a*(1.f/512.f);
      float var  = bb*(1.f/512.f) - mean*mean;
      red[8]=mean; red[9]=rsqrtf(var + 1e-5f);
    }
    __syncthreads();
    float mean = red[8], inv = red[9];
    int t = tid & 63;
    int c0 = g*8 + (tid>>6), c1 = c0 + 4;
    size_t rowb = ((size_t)n*T_ + t)*C_;
    ht[rowb + c0] = f2bf((v0-mean)*inv*nsc[c0] + nbi[c0]);
    ht[rowb + c1] = f2bf((v1-mean)*inv*nsc[c1] + nbi[c1]);
    return;
  }
  // -------- tproj
  {
    int b3k = blk - 2368;
    int b = b3k >> 6, ob = b3k & 63;
    float* w2s = smem;
    float* red = smem + 4096;
    const float* w2p = w2 + (size_t)ob*4*1024;
    #pragma unroll
    for (int r = 0; r < 16; r++) w2s[r*256 + tid] = w2p[r*256 + tid];
    __syncthreads();
    int t = tid & 63, eq = tid >> 6;
    const float* tep = temb + ((size_t)b*1024 + eq*256)*64 + t;
    const float* wq  = w2s + eq*256;
    float acc[4] = {0.f,0.f,0.f,0.f};
    #pragma unroll 4
    for (int i = 0; i < 256; i += 4) {
      float tv0 = tep[(i+0)*64];
      float tv1 = tep[(i+1)*64];
      float tv2 = tep[(i+2)*64];
      float tv3 = tep[(i+3)*64];
      #pragma unroll
      for (int j = 0; j < 4; j++) {
        float4 w4 = *(const float4*)&wq[j*1024 + i];
        acc[j] = fmaf(w4.x, tv0, acc[j]);
        acc[j] = fmaf(w4.y, tv1, acc[j]);
        acc[j] = fmaf(w4.z, tv2, acc[j]);
        acc[j] = fmaf(w4.w, tv3, acc[j]);
      }
    }
    #pragma unroll
    for (int j=0;j<4;j++) red[(eq*4+j)*64 + t] = acc[j];
    __syncthreads();
    if (tid < 64) {
      #pragma unroll
      for (int j=0;j<4;j++){
        int o = ob*4 + j;
        float v = red[j*64+tid]+red[(4+j)*64+tid]+red[(8+j)*64+tid]+red[(12+j)*64+tid];
        tp[((size_t)b*256+o)*64 + tid] = v + b2[o];
      }
    }
  }
}

// ---------------------------------------------------------------- MFMA GEMM
__global__ __launch_bounds__(256) void k_mm(
    const ushort* __restrict__ Wb, const ushort* __restrict__ Inb,
    const float* __restrict__ bias, const float* __restrict__ resid,
    float* __restrict__ Out, int oblocks, int Ototal)
{
  int blk = blockIdx.x;
  int n = blk / oblocks, ob = blk - n*oblocks;
  int tid = threadIdx.x;
  int lane = tid & 63, w = tid >> 6;
  int o0 = ob*64 + w*16;
  int r = lane & 15, kg = lane >> 4;
  const ushort* wp = Wb + (size_t)(o0 + r)*256 + kg*8;
  const ushort* ip = Inb + ((size_t)n*64 + r)*256 + kg*8;
  f32x4 acc[4];
  #pragma unroll
  for (int j=0;j<4;j++) acc[j] = (f32x4){0.f,0.f,0.f,0.f};
  #pragma unroll
  for (int ks = 0; ks < 8; ks++) {
    bf16x8 a = *(const bf16x8*)(wp + ks*32);
    #pragma unroll
    for (int j = 0; j < 4; j++) {
      bf16x8 b = *(const bf16x8*)(ip + (size_t)j*16*256 + ks*32);
      acc[j] = __builtin_amdgcn_mfma_f32_16x16x32_bf16(a, b, acc[j], 0, 0, 0);
    }
  }
  #pragma unroll
  for (int j = 0; j < 4; j++) {
    #pragma unroll
    for (int rr = 0; rr < 4; rr++) {
      int o = o0 + kg*4 + rr;
      size_t idx = ((size_t)n*Ototal + o)*64 + j*16 + r;
      float v = acc[j][rr] + bias[o];
      if (resid) v += resid[idx];
      Out[idx] = v;
    }
  }
}

// ---------------------------------------------------------------- scores+wa
// blocks [0,512): es[n,h,t,s] = mask*exp(qk/sqrt(32))  (bf16)
// blocks [512,768): wamm -> ew (bf16)
__global__ __launch_bounds__(256) void k_sw(
    const float* __restrict__ qkv, ushort* __restrict__ es,
    const float* __restrict__ amask,
    const int* __restrict__ fi, const float* __restrict__ w1,
    const float* __restrict__ b1, const float* __restrict__ tp,
    const ushort* __restrict__ w3b, const float* __restrict__ b3,
    ushort* __restrict__ ew)
{
  __shared__ char smem[33536];
  int blk = blockIdx.x;
  int tid = threadIdx.x;
  if (blk < 512) {
    // -------- scores -> es (masked, bf16)
    int n = blk >> 3, hh = blk & 7;
    float* qs = (float*)smem;
    float* ks = qs + 2048;
    const float* base = qkv + (size_t)n*(768*64);
    for (int i=tid; i<2048; i+=256){
      int cq = i>>6, tt = i&63;
      qs[i] = base[(cq*8+hh)*64 + tt];
      ks[i] = base[(256 + cq*8+hh)*64 + tt];
    }
    __syncthreads();
    int s  = tid & 63;
    int t4 = __builtin_amdgcn_readfirstlane(tid>>6);
    float msk = amask[(n >> 5)*64 + s];
    float acc[16];
    #pragma unroll
    for (int j=0;j<16;j++) acc[j]=0.f;
    for (int cq=0;cq<32;cq++){
      float kv = ks[cq*64+s];
      #pragma unroll
      for (int j=0;j<16;j++) acc[j] = fmaf(qs[cq*64 + t4*16 + j], kv, acc[j]);
    }
    ushort* op = es + (size_t)blk*4096;
    const float sc = 0.17677669529663687f; // 1/sqrt(32)
    #pragma unroll
    for (int j=0;j<16;j++)
      op[(t4*16+j)*64 + s] = f2bf(msk > 0.f ? __expf(acc[j]*sc) : 0.f);
    return;
  }
  // -------- wamm -> ew (bf16)
  {
    int blk2 = blk - 512;              // ((b*64 + t)*2 + oh)
    int oh = blk2 & 1; int bt = blk2 >> 1;
    int b = bt >> 6, t = bt & 63;
    float* l0 = (float*)smem;
    float* l1 = l0 + 64;
    float* l2 = l1 + 64;
    ushort* Ebuf = (ushort*)(smem + 768);
    if (tid < 64){
      int rel = fi[b*64+tid] - fi[b*64+t];
      float r0 = rel>0 ? (float)rel   : 0.f;
      float r1 = rel<0 ? (float)(-rel): 0.f;
      l0[tid] = log1pf(r0);
      l1[tid] = log1pf(r1);
      l2[tid] = (rel==0) ? 0.6931471805599453f : 0.f;
    }
    __syncthreads();
    int s = tid & 63;
    int iq = __builtin_amdgcn_readfirstlane(tid >> 6);
    float L0 = l0[s], L1 = l1[s], L2 = l2[s];
    #pragma unroll
    for (int c8 = 0; c8 < 8; c8++){
      int chunk = iq*8 + c8;
      int ibase = chunk*8;
      u16x8 pack;
      #pragma unroll
      for (int e = 0; e < 8; e++){
        int i = ibase + e;
        float bb = b1[i] + tp[((size_t)b*256 + i)*64 + t];
        float evv = fmaf(w1[i*3], L0, fmaf(w1[i*3+1], L1, fmaf(w1[i*3+2], L2, bb)));
        pack[e] = f2bf(fmaxf(evv, 0.f));
      }
      int csw = chunk ^ (s & 31);
      *(u16x8*)&Ebuf[s*256 + csw*8] = pack;
    }
    __syncthreads();
    int lane = tid & 63, w = tid >> 6;
    int r = lane & 15, kg = lane >> 4;
    int o0 = oh*128 + w*32;
    f32x4 acc[2][4];
    #pragma unroll
    for (int m=0;m<2;m++)
      #pragma unroll
      for (int j=0;j<4;j++) acc[m][j] = (f32x4){0.f,0.f,0.f,0.f};
    #pragma unroll
    for (int ks8 = 0; ks8 < 8; ks8++){
      bf16x8 a0 = *(const bf16x8*)(w3b + (size_t)(o0 +      r)*256 + kg*8 + ks8*32);
      bf16x8 a1 = *(const bf16x8*)(w3b + (size_t)(o0 + 16 + r)*256 + kg*8 + ks8*32);
      #pragma unroll
      for (int j=0;j<4;j++){
        int srow = j*16 + r;
        int chunk = (kg + ks8*4) ^ (srow & 31);
        bf16x8 bfr = *(const bf16x8*)&Ebuf[srow*256 + chunk*8];
        acc[0][j] = __builtin_amdgcn_mfma_f32_16x16x32_bf16(a0, bfr, acc[0][j], 0, 0, 0);
        acc[1][j] = __builtin_amdgcn_mfma_f32_16x16x32_bf16(a1, bfr, acc[1][j], 0, 0, 0);
      }
    }
    #pragma unroll
    for (int m=0;m<2;m++){
      #pragma unroll
      for (int j=0;j<4;j++){
        #pragma unroll
        for (int rr=0;rr<4;rr++){
          int o = o0 + m*16 + kg*4 + rr;
          int scol = j*16 + r;
          ew[((size_t)(b*256+o))*4096 + t*64 + scol] = f2bf(__expf(acc[m][j][rr] + b3[o]));
        }
      }
    }
  }
}

// ---------------------------------------------------------------- softmax+PV
// hv_t[n,t,c] (bf16) = sum_s es[n,h(c),t,s]*ew[b,c,t,s]*v[n,c,s] / sum es*ew
// XCD swizzle: all 64 blocks of one (b,h) land on one XCD (2 groups/XCD,
// es+ew+v working set ~2.5 MB < 4 MB L2). es/ew bf16, cvt at staging.
__global__ __launch_bounds__(256) void k_attn(
    const ushort* __restrict__ es, const ushort* __restrict__ ew,
    const float* __restrict__ qkv, ushort* __restrict__ hv_t)
{
  int i = blockIdx.x;            // 1024
  int xcd = i & 7, j0 = i >> 3;  // j0 in [0,128)
  int g = xcd + ((j0 >> 6) << 3);  // (b*8+h) group, 0..15
  int w64 = j0 & 63;
  int b = g >> 3, hh = g & 7;
  int dq = w64 >> 3, cs = w64 & 7;
  int tid = threadIdx.x;
  int t  = tid & 63;
  int dj = __builtin_amdgcn_readfirstlane(tid >> 6);
  int n  = b*D_ + dq*4 + dj;
  __shared__ float4 ewl[64][16];   // [t][k^(t&15)] swizzled
  __shared__ float4 vl4[4][16];
  float4 esr[16];
  {
    const u16x8* sp = (const u16x8*)(es + ((size_t)(n*8 + hh))*4096 + (size_t)t*64);
    #pragma unroll
    for (int k8=0;k8<8;k8++){
      u16x8 e8 = sp[k8];
      float4 lo, hi;
      lo.x=bf2f(e8[0]); lo.y=bf2f(e8[1]); lo.z=bf2f(e8[2]); lo.w=bf2f(e8[3]);
      hi.x=bf2f(e8[4]); hi.y=bf2f(e8[5]); hi.z=bf2f(e8[6]); hi.w=bf2f(e8[7]);
      esr[2*k8] = lo; esr[2*k8+1] = hi;
    }
  }
  int vd = tid >> 4, vk = tid & 15;          // v stage coords (tid<64)
  u16x8 rew[2]; float4 rv;
  // prologue: load tiles for ci=0
  {
    int c = cs*32 + hh;
    const u16x8* wap = (const u16x8*)(ew + ((size_t)(b*256 + c))*4096);
    rew[0] = wap[tid]; rew[1] = wap[tid+256];
    if (tid < 64)
      rv = *(const float4*)(qkv + ((size_t)(b*D_ + dq*4 + vd)*768 + 512 + c)*64 + 4*vk);
  }
  for (int ci=0; ci<4; ci++){
    __syncthreads();
    #pragma unroll
    for (int i2=0;i2<2;i2++){
      int ch = tid + 256*i2;           // chunk of 8 ushorts
      int tr = ch >> 3, k8 = ch & 7;
      u16x8 e8 = rew[i2];
      float4 lo, hi;
      lo.x=bf2f(e8[0]); lo.y=bf2f(e8[1]); lo.z=bf2f(e8[2]); lo.w=bf2f(e8[3]);
      hi.x=bf2f(e8[4]); hi.y=bf2f(e8[5]); hi.z=bf2f(e8[6]); hi.w=bf2f(e8[7]);
      ewl[tr][(k8*2)   ^ (tr & 15)] = lo;
      ewl[tr][(k8*2+1) ^ (tr & 15)] = hi;
    }
    if (tid < 64) vl4[vd][vk] = rv;
    __syncthreads();
    if (ci < 3){
      int c = (cs*4 + ci + 1)*8 + hh;
      const u16x8* wap = (const u16x8*)(ew + ((size_t)(b*256 + c))*4096);
      rew[0] = wap[tid]; rew[1] = wap[tid+256];
      if (tid < 64)
        rv = *(const float4*)(qkv + ((size_t)(b*D_ + dq*4 + vd)*768 + 512 + c)*64 + 4*vk);
    }
    float sum = 0.f;
    float ax=0.f, ay=0.f, az=0.f, aw=0.f;
    #pragma unroll
    for (int k=0;k<16;k++){
      float4 e4 = esr[k];
      float4 w4 = ewl[t][k ^ (t & 15)];
      float4 v4 = vl4[dj][k];
      float px = e4.x*w4.x, py = e4.y*w4.y, pz = e4.z*w4.z, pw = e4.w*w4.w;
      sum += px+py+pz+pw;
      ax = fmaf(px, v4.x, ax);
      ay = fmaf(py, v4.y, ay);
      az = fmaf(pz, v4.z, az);
      aw = fmaf(pw, v4.w, aw);
    }
    float acc = (ax+ay)+(az+aw);
    int c = (cs*4 + ci)*8 + hh;
    hv_t[((size_t)n*64 + t)*256 + c] = f2bf(acc / sum);
  }
}

extern "C" void kernel_launch(void* const* d_in, const int* in_sizes, int n_in,
                              void* d_out, int out_size, void* d_ws, size_t ws_size,
                              hipStream_t stream) {
  const float* x     = (const float*)d_in[0];
  const float* temb  = (const float*)d_in[1];
  const int*   fi    = (const int*)  d_in[2];
  const float* amask = (const float*)d_in[3];
  const float* nsc   = (const float*)d_in[4];
  const float* nbi   = (const float*)d_in[5];
  const float* w_qkv = (const float*)d_in[6];
  const float* b_qkv = (const float*)d_in[7];
  const float* w1    = (const float*)d_in[8];
  const float* b1    = (const float*)d_in[9];
  const float* w2    = (const float*)d_in[10];
  const float* b2    = (const float*)d_in[11];
  const float* w3    = (const float*)d_in[12];
  const float* b3    = (const float*)d_in[13];
  const float* wp    = (const float*)d_in[14];
  const float* bp    = (const float*)d_in[15];
  float* out = (float*)d_out;
  float* ws  = (float*)d_ws;

  float*  qkvb = ws;                          // 3,145,728 f
  float*  tpb  = qkvb + 3145728;              //    32,768 f
  ushort* esb  = (ushort*)(tpb + 32768);      // 2,097,152 us
  ushort* ewb  = esb + 2097152;               // 2,097,152 us
  ushort* htb  = ewb + 2097152;               // 1,048,576 us
  ushort* hvb  = htb + 1048576;               // 1,048,576 us
  ushort* wqb  = hvb + 1048576;               //   196,608 us
  ushort* wpb  = wqb + 196608;                //    65,536 us
  ushort* w3b  = wpb + 65536;                 //    65,536 us

  k_prep <<<2496, 256, 0, stream>>>(w_qkv, wp, w3, wqb, wpb, w3b,
                                    x, nsc, nbi, htb, temb, w2, b2, tpb);
  k_mm   <<<N_*12, 256, 0, stream>>>(wqb, htb, b_qkv, nullptr, qkvb, 12, 768);
  k_sw   <<<768, 256, 0, stream>>>(qkvb, esb, amask, fi, w1, b1, tpb, w3b, b3, ewb);
  k_attn <<<B_*H_*8*8, 256, 0, stream>>>(esb, ewb, qkvb, hvb);
  k_mm   <<<N_*4,  256, 0, stream>>>(wpb, hvb, bp, x, out, 4, 256);
}

// Round 7
// 75.560 us; speedup vs baseline: 4.2301x; 1.0023x over previous
//
#include <hip/hip_runtime.h>

#define B_ 2
#define D_ 32
#define C_ 256
#define T_ 64
#define TE_ 1024
#define H_ 8
#define N_ 64   // B_*D_

typedef __attribute__((ext_vector_type(8))) short bf16x8;
typedef __attribute__((ext_vector_type(8))) unsigned short u16x8;
typedef __attribute__((ext_vector_type(4))) float f32x4;

__device__ inline ushort f2bf(float x){
  unsigned u = __float_as_uint(x);
  unsigned r = u + 0x7FFFu + ((u>>16)&1u);
  return (ushort)(r>>16);
}
__device__ inline float bf2f(ushort u){
  return __uint_as_float(((unsigned)u)<<16);
}

// ---------------------------------------------------------------- prep
// blocks [0,192): cast w_qkv | [192,256): cast wp | [256,320): cast w3
// [320,2368): groupnorm | [2368,2496): tproj
__global__ __launch_bounds__(256) void k_prep(
    const float* __restrict__ w_qkv, const float* __restrict__ wp,
    const float* __restrict__ w3,
    ushort* __restrict__ wqb, ushort* __restrict__ wpb, ushort* __restrict__ w3b,
    const float* __restrict__ x, const float* __restrict__ nsc,
    const float* __restrict__ nbi, ushort* __restrict__ ht,
    const float* __restrict__ temb, const float* __restrict__ w2,
    const float* __restrict__ b2, float* __restrict__ tp)
{
  __shared__ float smem[5120];
  int blk = blockIdx.x;
  int tid = threadIdx.x;
  if (blk < 320) {
    const float* src; ushort* dst; int n4, i0;
    if (blk < 192)      { src = w_qkv; dst = wqb; n4 = 49152; i0 = blk; }
    else if (blk < 256) { src = wp;    dst = wpb; n4 = 16384; i0 = blk-192; }
    else                { src = w3;    dst = w3b; n4 = 16384; i0 = blk-256; }
    int i = i0*256 + tid;
    if (i < n4){
      float4 v = ((const float4*)src)[i];
      ushort4 o; o.x=f2bf(v.x); o.y=f2bf(v.y); o.z=f2bf(v.z); o.w=f2bf(v.w);
      ((ushort4*)dst)[i] = o;
    }
    return;
  }
  if (blk < 2368) {
    // -------- group norm: x (N,256,64) -> ht bf16 [n][t][c]
    int b2k = blk - 320;
    int n = b2k >> 5, g = b2k & 31;
    const float* xp = x + ((size_t)n*C_ + g*8) * T_;
    float v0 = xp[tid], v1 = xp[tid+256];
    float s = v0+v1, ss = v0*v0 + v1*v1;
    #pragma unroll
    for (int off=32; off; off>>=1) { s += __shfl_down(s,off); ss += __shfl_down(ss,off); }
    float* red = smem;
    int wid = tid>>6, lane = tid&63;
    if (lane==0){ red[wid]=s; red[4+wid]=ss; }
    __syncthreads();
    if (tid==0){
      float a  = red[0]+red[1]+red[2]+red[3];
      float bb = red[4]+red[5]+red[6]+red[7];
      float mean = a*(1.f/512.f);
      float var  = bb*(1.f/512.f) - mean*mean;
      red[8]=mean; red[9]=rsqrtf(var + 1e-5f);
    }
    __syncthreads();
    float mean = red[8], inv = red[9];
    int t = tid & 63;
    int c0 = g*8 + (tid>>6), c1 = c0 + 4;
    size_t rowb = ((size_t)n*T_ + t)*C_;
    ht[rowb + c0] = f2bf((v0-mean)*inv*nsc[c0] + nbi[c0]);
    ht[rowb + c1] = f2bf((v1-mean)*inv*nsc[c1] + nbi[c1]);
    return;
  }
  // -------- tproj
  {
    int b3k = blk - 2368;
    int b = b3k >> 6, ob = b3k & 63;
    float* w2s = smem;
    float* red = smem + 4096;
    const float* w2p = w2 + (size_t)ob*4*1024;
    #pragma unroll
    for (int r = 0; r < 16; r++) w2s[r*256 + tid] = w2p[r*256 + tid];
    __syncthreads();
    int t = tid & 63, eq = tid >> 6;
    const float* tep = temb + ((size_t)b*1024 + eq*256)*64 + t;
    const float* wq  = w2s + eq*256;
    float acc[4] = {0.f,0.f,0.f,0.f};
    #pragma unroll 4
    for (int i = 0; i < 256; i += 4) {
      float tv0 = tep[(i+0)*64];
      float tv1 = tep[(i+1)*64];
      float tv2 = tep[(i+2)*64];
      float tv3 = tep[(i+3)*64];
      #pragma unroll
      for (int j = 0; j < 4; j++) {
        float4 w4 = *(const float4*)&wq[j*1024 + i];
        acc[j] = fmaf(w4.x, tv0, acc[j]);
        acc[j] = fmaf(w4.y, tv1, acc[j]);
        acc[j] = fmaf(w4.z, tv2, acc[j]);
        acc[j] = fmaf(w4.w, tv3, acc[j]);
      }
    }
    #pragma unroll
    for (int j=0;j<4;j++) red[(eq*4+j)*64 + t] = acc[j];
    __syncthreads();
    if (tid < 64) {
      #pragma unroll
      for (int j=0;j<4;j++){
        int o = ob*4 + j;
        float v = red[j*64+tid]+red[(4+j)*64+tid]+red[(8+j)*64+tid]+red[(12+j)*64+tid];
        tp[((size_t)b*256+o)*64 + tid] = v + b2[o];
      }
    }
  }
}

// ---------------------------------------------------------------- MFMA GEMM
// mode 0: Out fp32 = acc + bias + resid   (proj)
// mode 1: Out bf16 = (acc + bias) * (o<512 ? 32^-0.25 : 1)   (qkv, q/k pre-scaled)
__global__ __launch_bounds__(256) void k_mm(
    const ushort* __restrict__ Wb, const ushort* __restrict__ Inb,
    const float* __restrict__ bias, const float* __restrict__ resid,
    void* __restrict__ OutV, int oblocks, int Ototal, int mode)
{
  int blk = blockIdx.x;
  int n = blk / oblocks, ob = blk - n*oblocks;
  int tid = threadIdx.x;
  int lane = tid & 63, w = tid >> 6;
  int o0 = ob*64 + w*16;
  int r = lane & 15, kg = lane >> 4;
  const ushort* wp = Wb + (size_t)(o0 + r)*256 + kg*8;
  const ushort* ip = Inb + ((size_t)n*64 + r)*256 + kg*8;
  f32x4 acc[4];
  #pragma unroll
  for (int j=0;j<4;j++) acc[j] = (f32x4){0.f,0.f,0.f,0.f};
  #pragma unroll
  for (int ks = 0; ks < 8; ks++) {
    bf16x8 a = *(const bf16x8*)(wp + ks*32);
    #pragma unroll
    for (int j = 0; j < 4; j++) {
      bf16x8 b = *(const bf16x8*)(ip + (size_t)j*16*256 + ks*32);
      acc[j] = __builtin_amdgcn_mfma_f32_16x16x32_bf16(a, b, acc[j], 0, 0, 0);
    }
  }
  #pragma unroll
  for (int j = 0; j < 4; j++) {
    #pragma unroll
    for (int rr = 0; rr < 4; rr++) {
      int o = o0 + kg*4 + rr;
      size_t idx = ((size_t)n*Ototal + o)*64 + j*16 + r;
      float v = acc[j][rr] + bias[o];
      if (mode == 0) {
        v += resid[idx];
        ((float*)OutV)[idx] = v;
      } else {
        if (o < 512) v *= 0.42044820762685725f;  // 32^-0.25
        ((ushort*)OutV)[idx] = f2bf(v);
      }
    }
  }
}

// ---------------------------------------------------------------- scores+wa
// blocks [0,512): es[n,h,t,s] = mask * exp(sum q*k)  (q,k bf16 pre-scaled)
// blocks [512,768): wamm -> ew (bf16)
__global__ __launch_bounds__(256) void k_sw(
    const ushort* __restrict__ qkv, ushort* __restrict__ es,
    const float* __restrict__ amask,
    const int* __restrict__ fi, const float* __restrict__ w1,
    const float* __restrict__ b1, const float* __restrict__ tp,
    const ushort* __restrict__ w3b, const float* __restrict__ b3,
    ushort* __restrict__ ew)
{
  __shared__ char smem[33536];
  int blk = blockIdx.x;
  int tid = threadIdx.x;
  if (blk < 512) {
    // -------- scores -> es (masked, bf16)
    int n = blk >> 3, hh = blk & 7;
    float* qs = (float*)smem;
    float* ks = qs + 2048;
    const ushort* base = qkv + (size_t)n*(768*64);
    for (int i=tid; i<2048; i+=256){
      int cq = i>>6, tt = i&63;
      qs[i] = bf2f(base[(cq*8+hh)*64 + tt]);
      ks[i] = bf2f(base[(256 + cq*8+hh)*64 + tt]);
    }
    __syncthreads();
    int s  = tid & 63;
    int t4 = __builtin_amdgcn_readfirstlane(tid>>6);
    float msk = amask[(n >> 5)*64 + s];
    float acc[16];
    #pragma unroll
    for (int j=0;j<16;j++) acc[j]=0.f;
    for (int cq=0;cq<32;cq++){
      float kv = ks[cq*64+s];
      #pragma unroll
      for (int j=0;j<16;j++) acc[j] = fmaf(qs[cq*64 + t4*16 + j], kv, acc[j]);
    }
    ushort* op = es + (size_t)blk*4096;
    #pragma unroll
    for (int j=0;j<16;j++)
      op[(t4*16+j)*64 + s] = f2bf(msk > 0.f ? __expf(acc[j]) : 0.f);
    return;
  }
  // -------- wamm -> ew (bf16)
  {
    int blk2 = blk - 512;              // ((b*64 + t)*2 + oh)
    int oh = blk2 & 1; int bt = blk2 >> 1;
    int b = bt >> 6, t = bt & 63;
    float* l0 = (float*)smem;
    float* l1 = l0 + 64;
    float* l2 = l1 + 64;
    ushort* Ebuf = (ushort*)(smem + 768);
    if (tid < 64){
      int rel = fi[b*64+tid] - fi[b*64+t];
      float r0 = rel>0 ? (float)rel   : 0.f;
      float r1 = rel<0 ? (float)(-rel): 0.f;
      l0[tid] = log1pf(r0);
      l1[tid] = log1pf(r1);
      l2[tid] = (rel==0) ? 0.6931471805599453f : 0.f;
    }
    __syncthreads();
    int s = tid & 63;
    int iq = __builtin_amdgcn_readfirstlane(tid >> 6);
    float L0 = l0[s], L1 = l1[s], L2 = l2[s];
    #pragma unroll
    for (int c8 = 0; c8 < 8; c8++){
      int chunk = iq*8 + c8;
      int ibase = chunk*8;
      u16x8 pack;
      #pragma unroll
      for (int e = 0; e < 8; e++){
        int i = ibase + e;
        float bb = b1[i] + tp[((size_t)b*256 + i)*64 + t];
        float evv = fmaf(w1[i*3], L0, fmaf(w1[i*3+1], L1, fmaf(w1[i*3+2], L2, bb)));
        pack[e] = f2bf(fmaxf(evv, 0.f));
      }
      int csw = chunk ^ (s & 31);
      *(u16x8*)&Ebuf[s*256 + csw*8] = pack;
    }
    __syncthreads();
    int lane = tid & 63, w = tid >> 6;
    int r = lane & 15, kg = lane >> 4;
    int o0 = oh*128 + w*32;
    f32x4 acc[2][4];
    #pragma unroll
    for (int m=0;m<2;m++)
      #pragma unroll
      for (int j=0;j<4;j++) acc[m][j] = (f32x4){0.f,0.f,0.f,0.f};
    #pragma unroll
    for (int ks8 = 0; ks8 < 8; ks8++){
      bf16x8 a0 = *(const bf16x8*)(w3b + (size_t)(o0 +      r)*256 + kg*8 + ks8*32);
      bf16x8 a1 = *(const bf16x8*)(w3b + (size_t)(o0 + 16 + r)*256 + kg*8 + ks8*32);
      #pragma unroll
      for (int j=0;j<4;j++){
        int srow = j*16 + r;
        int chunk = (kg + ks8*4) ^ (srow & 31);
        bf16x8 bfr = *(const bf16x8*)&Ebuf[srow*256 + chunk*8];
        acc[0][j] = __builtin_amdgcn_mfma_f32_16x16x32_bf16(a0, bfr, acc[0][j], 0, 0, 0);
        acc[1][j] = __builtin_amdgcn_mfma_f32_16x16x32_bf16(a1, bfr, acc[1][j], 0, 0, 0);
      }
    }
    #pragma unroll
    for (int m=0;m<2;m++){
      #pragma unroll
      for (int j=0;j<4;j++){
        #pragma unroll
        for (int rr=0;rr<4;rr++){
          int o = o0 + m*16 + kg*4 + rr;
          int scol = j*16 + r;
          ew[((size_t)(b*256+o))*4096 + t*64 + scol] = f2bf(__expf(acc[m][j][rr] + b3[o]));
        }
      }
    }
  }
}

// ---------------------------------------------------------------- softmax+PV
// hv_t[n,t,c] (bf16) = sum_s es[n,h(c),t,s]*ew[b,c,t,s]*v[n,c,s] / sum es*ew
// XCD swizzle: all 64 blocks of one (b,h) land on one XCD.
__global__ __launch_bounds__(256) void k_attn(
    const ushort* __restrict__ es, const ushort* __restrict__ ew,
    const ushort* __restrict__ qkv, ushort* __restrict__ hv_t)
{
  int i = blockIdx.x;            // 1024
  int xcd = i & 7, j0 = i >> 3;  // j0 in [0,128)
  int g = xcd + ((j0 >> 6) << 3);  // (b*8+h) group, 0..15
  int w64 = j0 & 63;
  int b = g >> 3, hh = g & 7;
  int dq = w64 >> 3, cs = w64 & 7;
  int tid = threadIdx.x;
  int t  = tid & 63;
  int dj = __builtin_amdgcn_readfirstlane(tid >> 6);
  int n  = b*D_ + dq*4 + dj;
  __shared__ float4 ewl[64][16];   // [t][k^(t&15)] swizzled
  __shared__ float4 vl4[4][16];
  float4 esr[16];
  {
    const u16x8* sp = (const u16x8*)(es + ((size_t)(n*8 + hh))*4096 + (size_t)t*64);
    #pragma unroll
    for (int k8=0;k8<8;k8++){
      u16x8 e8 = sp[k8];
      float4 lo, hi;
      lo.x=bf2f(e8[0]); lo.y=bf2f(e8[1]); lo.z=bf2f(e8[2]); lo.w=bf2f(e8[3]);
      hi.x=bf2f(e8[4]); hi.y=bf2f(e8[5]); hi.z=bf2f(e8[6]); hi.w=bf2f(e8[7]);
      esr[2*k8] = lo; esr[2*k8+1] = hi;
    }
  }
  int vd = tid >> 4, vk = tid & 15;          // v stage coords (tid<64)
  u16x8 rew[2]; ushort4 rv;
  // prologue: load tiles for ci=0
  {
    int c = cs*32 + hh;
    const u16x8* wap = (const u16x8*)(ew + ((size_t)(b*256 + c))*4096);
    rew[0] = wap[tid]; rew[1] = wap[tid+256];
    if (tid < 64)
      rv = *(const ushort4*)(qkv + ((size_t)(b*D_ + dq*4 + vd)*768 + 512 + c)*64 + 4*vk);
  }
  for (int ci=0; ci<4; ci++){
    __syncthreads();
    #pragma unroll
    for (int i2=0;i2<2;i2++){
      int ch = tid + 256*i2;           // chunk of 8 ushorts
      int tr = ch >> 3, k8 = ch & 7;
      u16x8 e8 = rew[i2];
      float4 lo, hi;
      lo.x=bf2f(e8[0]); lo.y=bf2f(e8[1]); lo.z=bf2f(e8[2]); lo.w=bf2f(e8[3]);
      hi.x=bf2f(e8[4]); hi.y=bf2f(e8[5]); hi.z=bf2f(e8[6]); hi.w=bf2f(e8[7]);
      ewl[tr][(k8*2)   ^ (tr & 15)] = lo;
      ewl[tr][(k8*2+1) ^ (tr & 15)] = hi;
    }
    if (tid < 64){
      float4 vv; vv.x=bf2f(rv.x); vv.y=bf2f(rv.y); vv.z=bf2f(rv.z); vv.w=bf2f(rv.w);
      vl4[vd][vk] = vv;
    }
    __syncthreads();
    if (ci < 3){
      int c = (cs*4 + ci + 1)*8 + hh;
      const u16x8* wap = (const u16x8*)(ew + ((size_t)(b*256 + c))*4096);
      rew[0] = wap[tid]; rew[1] = wap[tid+256];
      if (tid < 64)
        rv = *(const ushort4*)(qkv + ((size_t)(b*D_ + dq*4 + vd)*768 + 512 + c)*64 + 4*vk);
    }
    float sum = 0.f;
    float ax=0.f, ay=0.f, az=0.f, aw=0.f;
    #pragma unroll
    for (int k=0;k<16;k++){
      float4 e4 = esr[k];
      float4 w4 = ewl[t][k ^ (t & 15)];
      float4 v4 = vl4[dj][k];
      float px = e4.x*w4.x, py = e4.y*w4.y, pz = e4.z*w4.z, pw = e4.w*w4.w;
      sum += px+py+pz+pw;
      ax = fmaf(px, v4.x, ax);
      ay = fmaf(py, v4.y, ay);
      az = fmaf(pz, v4.z, az);
      aw = fmaf(pw, v4.w, aw);
    }
    float acc = (ax+ay)+(az+aw);
    int c = (cs*4 + ci)*8 + hh;
    hv_t[((size_t)n*64 + t)*256 + c] = f2bf(acc / sum);
  }
}

extern "C" void kernel_launch(void* const* d_in, const int* in_sizes, int n_in,
                              void* d_out, int out_size, void* d_ws, size_t ws_size,
                              hipStream_t stream) {
  const float* x     = (const float*)d_in[0];
  const float* temb  = (const float*)d_in[1];
  const int*   fi    = (const int*)  d_in[2];
  const float* amask = (const float*)d_in[3];
  const float* nsc   = (const float*)d_in[4];
  const float* nbi   = (const float*)d_in[5];
  const float* w_qkv = (const float*)d_in[6];
  const float* b_qkv = (const float*)d_in[7];
  const float* w1    = (const float*)d_in[8];
  const float* b1    = (const float*)d_in[9];
  const float* w2    = (const float*)d_in[10];
  const float* b2    = (const float*)d_in[11];
  const float* w3    = (const float*)d_in[12];
  const float* b3    = (const float*)d_in[13];
  const float* wp    = (const float*)d_in[14];
  const float* bp    = (const float*)d_in[15];
  float* out = (float*)d_out;

  ushort* qkvb = (ushort*)d_ws;               // 3,145,728 us
  float*  tpb  = (float*)(qkvb + 3145728);    //    32,768 f
  ushort* esb  = (ushort*)(tpb + 32768);      // 2,097,152 us
  ushort* ewb  = esb + 2097152;               // 2,097,152 us
  ushort* htb  = ewb + 2097152;               // 1,048,576 us
  ushort* hvb  = htb + 1048576;               // 1,048,576 us
  ushort* wqb  = hvb + 1048576;               //   196,608 us
  ushort* wpb  = wqb + 196608;                //    65,536 us
  ushort* w3b  = wpb + 65536;                 //    65,536 us

  k_prep <<<2496, 256, 0, stream>>>(w_qkv, wp, w3, wqb, wpb, w3b,
                                    x, nsc, nbi, htb, temb, w2, b2, tpb);
  k_mm   <<<N_*12, 256, 0, stream>>>(wqb, htb, b_qkv, nullptr, qkvb, 12, 768, 1);
  k_sw   <<<768, 256, 0, stream>>>(qkvb, esb, amask, fi, w1, b1, tpb, w3b, b3, ewb);
  k_attn <<<B_*H_*8*8, 256, 0, stream>>>(esb, ewb, qkvb, hvb);
  k_mm   <<<N_*4,  256, 0, stream>>>(wpb, hvb, bp, x, out, 4, 256, 0);
}

// Round 8
// 64.493 us; speedup vs baseline: 4.9560x; 1.1716x over previous
//
#include <hip/hip_runtime.h>

#define B_ 2
#define D_ 32
#define C_ 256
#define T_ 64
#define TE_ 1024
#define H_ 8
#define N_ 64   // B_*D_

typedef __attribute__((ext_vector_type(8))) short bf16x8;
typedef __attribute__((ext_vector_type(8))) unsigned short u16x8;
typedef __attribute__((ext_vector_type(4))) float f32x4;

__device__ inline ushort f2bf(float x){
  unsigned u = __float_as_uint(x);
  unsigned r = u + 0x7FFFu + ((u>>16)&1u);
  return (ushort)(r>>16);
}
__device__ inline float bf2f(ushort u){
  return __uint_as_float(((unsigned)u)<<16);
}

// ---------------------------------------------------------------- prep
// blocks [0,192): cast w_qkv | [192,256): cast wp -> Wr (K'=h*32+cq reorder)
// [256,320): cast w3 | [320,2368): groupnorm | [2368,2496): tproj
__global__ __launch_bounds__(256) void k_prep(
    const float* __restrict__ w_qkv, const float* __restrict__ wp,
    const float* __restrict__ w3,
    ushort* __restrict__ wqb, ushort* __restrict__ wpr, ushort* __restrict__ w3b,
    const float* __restrict__ x, const float* __restrict__ nsc,
    const float* __restrict__ nbi, ushort* __restrict__ ht,
    const float* __restrict__ temb, const float* __restrict__ w2,
    const float* __restrict__ b2, float* __restrict__ tp)
{
  __shared__ float smem[5120];
  int blk = blockIdx.x;
  int tid = threadIdx.x;
  if (blk < 320) {
    if (blk < 192) {
      int i = blk*256 + tid;
      float4 v = ((const float4*)w_qkv)[i];
      ushort4 o; o.x=f2bf(v.x); o.y=f2bf(v.y); o.z=f2bf(v.z); o.w=f2bf(v.w);
      ((ushort4*)wqb)[i] = o;
    } else if (blk < 256) {
      // wp [o][c] -> Wr [o][(c&7)*32 + (c>>3)]
      int i = (blk-192)*256 + tid;     // float4 index over [o][c]
      float4 v = ((const float4*)wp)[i];
      int o = i >> 6, c0 = (i & 63)*4;
      #pragma unroll
      for (int e=0;e<4;e++){
        int c = c0+e;
        float vv = (e==0)?v.x:(e==1)?v.y:(e==2)?v.z:v.w;
        wpr[o*256 + (c&7)*32 + (c>>3)] = f2bf(vv);
      }
    } else {
      int i = (blk-256)*256 + tid;
      float4 v = ((const float4*)w3)[i];
      ushort4 o; o.x=f2bf(v.x); o.y=f2bf(v.y); o.z=f2bf(v.z); o.w=f2bf(v.w);
      ((ushort4*)w3b)[i] = o;
    }
    return;
  }
  if (blk < 2368) {
    // -------- group norm: x (N,256,64) -> ht bf16 [n][t][c], 16B stores
    int b2k = blk - 320;
    int n = b2k >> 5, g = b2k & 31;
    const float* xp = x + ((size_t)n*C_ + g*8) * T_;
    float v0 = xp[tid], v1 = xp[tid+256];
    float s = v0+v1, ss = v0*v0 + v1*v1;
    #pragma unroll
    for (int off=32; off; off>>=1) { s += __shfl_down(s,off); ss += __shfl_down(ss,off); }
    float* red = smem;
    ushort* gbuf = (ushort*)(smem + 16);   // 512 ushorts, no overlap with red
    int wid = tid>>6, lane = tid&63;
    if (lane==0){ red[wid]=s; red[4+wid]=ss; }
    __syncthreads();
    if (tid==0){
      float a  = red[0]+red[1]+red[2]+red[3];
      float bb = red[4]+red[5]+red[6]+red[7];
      float mean = a*(1.f/512.f);
      float var  = bb*(1.f/512.f) - mean*mean;
      red[8]=mean; red[9]=rsqrtf(var + 1e-5f);
    }
    __syncthreads();
    float mean = red[8], inv = red[9];
    int t = tid & 63, w = tid >> 6;
    int c0 = g*8 + w, c1 = c0 + 4;
    gbuf[w*64 + t]     = f2bf((v0-mean)*inv*nsc[c0] + nbi[c0]);
    gbuf[(w+4)*64 + t] = f2bf((v1-mean)*inv*nsc[c1] + nbi[c1]);
    __syncthreads();
    if (tid < 64){
      u16x8 pk;
      #pragma unroll
      for (int i=0;i<8;i++) pk[i] = gbuf[i*64 + tid];
      *(u16x8*)&ht[((size_t)n*T_ + tid)*C_ + g*8] = pk;
    }
    return;
  }
  // -------- tproj
  {
    int b3k = blk - 2368;
    int b = b3k >> 6, ob = b3k & 63;
    float* w2s = smem;
    float* red = smem + 4096;
    const float* w2p = w2 + (size_t)ob*4*1024;
    #pragma unroll
    for (int r = 0; r < 16; r++) w2s[r*256 + tid] = w2p[r*256 + tid];
    __syncthreads();
    int t = tid & 63, eq = tid >> 6;
    const float* tep = temb + ((size_t)b*1024 + eq*256)*64 + t;
    const float* wq  = w2s + eq*256;
    float acc[4] = {0.f,0.f,0.f,0.f};
    #pragma unroll 4
    for (int i = 0; i < 256; i += 4) {
      float tv0 = tep[(i+0)*64];
      float tv1 = tep[(i+1)*64];
      float tv2 = tep[(i+2)*64];
      float tv3 = tep[(i+3)*64];
      #pragma unroll
      for (int j = 0; j < 4; j++) {
        float4 w4 = *(const float4*)&wq[j*1024 + i];
        acc[j] = fmaf(w4.x, tv0, acc[j]);
        acc[j] = fmaf(w4.y, tv1, acc[j]);
        acc[j] = fmaf(w4.z, tv2, acc[j]);
        acc[j] = fmaf(w4.w, tv3, acc[j]);
      }
    }
    #pragma unroll
    for (int j=0;j<4;j++) red[(eq*4+j)*64 + t] = acc[j];
    __syncthreads();
    if (tid < 64) {
      #pragma unroll
      for (int j=0;j<4;j++){
        int o = ob*4 + j;
        float v = red[j*64+tid]+red[(4+j)*64+tid]+red[(8+j)*64+tid]+red[(12+j)*64+tid];
        tp[((size_t)b*256+o)*64 + tid] = v + b2[o];
      }
    }
  }
}

// ---------------------------------------------------------------- qkv GEMM
// Out bf16 = (acc + bias) * (o<512 ? 32^-0.25 : 1)
__global__ __launch_bounds__(256) void k_mm(
    const ushort* __restrict__ Wb, const ushort* __restrict__ Inb,
    const float* __restrict__ bias, ushort* __restrict__ Out)
{
  int blk = blockIdx.x;
  int n = blk / 12, ob = blk - n*12;
  int tid = threadIdx.x;
  int lane = tid & 63, w = tid >> 6;
  int o0 = ob*64 + w*16;
  int r = lane & 15, kg = lane >> 4;
  const ushort* wp = Wb + (size_t)(o0 + r)*256 + kg*8;
  const ushort* ip = Inb + ((size_t)n*64 + r)*256 + kg*8;
  f32x4 acc[4];
  #pragma unroll
  for (int j=0;j<4;j++) acc[j] = (f32x4){0.f,0.f,0.f,0.f};
  #pragma unroll
  for (int ks = 0; ks < 8; ks++) {
    bf16x8 a = *(const bf16x8*)(wp + ks*32);
    #pragma unroll
    for (int j = 0; j < 4; j++) {
      bf16x8 b = *(const bf16x8*)(ip + (size_t)j*16*256 + ks*32);
      acc[j] = __builtin_amdgcn_mfma_f32_16x16x32_bf16(a, b, acc[j], 0, 0, 0);
    }
  }
  #pragma unroll
  for (int j = 0; j < 4; j++) {
    #pragma unroll
    for (int rr = 0; rr < 4; rr++) {
      int o = o0 + kg*4 + rr;
      size_t idx = ((size_t)n*768 + o)*64 + j*16 + r;
      float v = acc[j][rr] + bias[o];
      if (o < 512) v *= 0.42044820762685725f;  // 32^-0.25
      Out[idx] = f2bf(v);
    }
  }
}

// ---------------------------------------------------------------- scores+wa
// blocks [0,512): es[n,h,t,s] = mask * exp(sum q*k)  (q,k bf16 pre-scaled)
// blocks [512,768): wamm -> ew (bf16)
__global__ __launch_bounds__(256) void k_sw(
    const ushort* __restrict__ qkv, ushort* __restrict__ es,
    const float* __restrict__ amask,
    const int* __restrict__ fi, const float* __restrict__ w1,
    const float* __restrict__ b1, const float* __restrict__ tp,
    const ushort* __restrict__ w3b, const float* __restrict__ b3,
    ushort* __restrict__ ew)
{
  __shared__ char smem[33536];
  int blk = blockIdx.x;
  int tid = threadIdx.x;
  if (blk < 512) {
    int n = blk >> 3, hh = blk & 7;
    float* qs = (float*)smem;
    float* ks = qs + 2048;
    const ushort* base = qkv + (size_t)n*(768*64);
    for (int i=tid; i<2048; i+=256){
      int cq = i>>6, tt = i&63;
      qs[i] = bf2f(base[(cq*8+hh)*64 + tt]);
      ks[i] = bf2f(base[(256 + cq*8+hh)*64 + tt]);
    }
    __syncthreads();
    int s  = tid & 63;
    int t4 = __builtin_amdgcn_readfirstlane(tid>>6);
    float msk = amask[(n >> 5)*64 + s];
    float acc[16];
    #pragma unroll
    for (int j=0;j<16;j++) acc[j]=0.f;
    for (int cq=0;cq<32;cq++){
      float kv = ks[cq*64+s];
      #pragma unroll
      for (int j=0;j<16;j++) acc[j] = fmaf(qs[cq*64 + t4*16 + j], kv, acc[j]);
    }
    ushort* op = es + (size_t)blk*4096;
    #pragma unroll
    for (int j=0;j<16;j++)
      op[(t4*16+j)*64 + s] = f2bf(msk > 0.f ? __expf(acc[j]) : 0.f);
    return;
  }
  {
    int blk2 = blk - 512;              // ((b*64 + t)*2 + oh)
    int oh = blk2 & 1; int bt = blk2 >> 1;
    int b = bt >> 6, t = bt & 63;
    float* l0 = (float*)smem;
    float* l1 = l0 + 64;
    float* l2 = l1 + 64;
    ushort* Ebuf = (ushort*)(smem + 768);
    if (tid < 64){
      int rel = fi[b*64+tid] - fi[b*64+t];
      float r0 = rel>0 ? (float)rel   : 0.f;
      float r1 = rel<0 ? (float)(-rel): 0.f;
      l0[tid] = log1pf(r0);
      l1[tid] = log1pf(r1);
      l2[tid] = (rel==0) ? 0.6931471805599453f : 0.f;
    }
    __syncthreads();
    int s = tid & 63;
    int iq = __builtin_amdgcn_readfirstlane(tid >> 6);
    float L0 = l0[s], L1 = l1[s], L2 = l2[s];
    #pragma unroll
    for (int c8 = 0; c8 < 8; c8++){
      int chunk = iq*8 + c8;
      int ibase = chunk*8;
      u16x8 pack;
      #pragma unroll
      for (int e = 0; e < 8; e++){
        int i = ibase + e;
        float bb = b1[i] + tp[((size_t)b*256 + i)*64 + t];
        float evv = fmaf(w1[i*3], L0, fmaf(w1[i*3+1], L1, fmaf(w1[i*3+2], L2, bb)));
        pack[e] = f2bf(fmaxf(evv, 0.f));
      }
      int csw = chunk ^ (s & 31);
      *(u16x8*)&Ebuf[s*256 + csw*8] = pack;
    }
    __syncthreads();
    int lane = tid & 63, w = tid >> 6;
    int r = lane & 15, kg = lane >> 4;
    int o0 = oh*128 + w*32;
    f32x4 acc[2][4];
    #pragma unroll
    for (int m=0;m<2;m++)
      #pragma unroll
      for (int j=0;j<4;j++) acc[m][j] = (f32x4){0.f,0.f,0.f,0.f};
    #pragma unroll
    for (int ks8 = 0; ks8 < 8; ks8++){
      bf16x8 a0 = *(const bf16x8*)(w3b + (size_t)(o0 +      r)*256 + kg*8 + ks8*32);
      bf16x8 a1 = *(const bf16x8*)(w3b + (size_t)(o0 + 16 + r)*256 + kg*8 + ks8*32);
      #pragma unroll
      for (int j=0;j<4;j++){
        int srow = j*16 + r;
        int chunk = (kg + ks8*4) ^ (srow & 31);
        bf16x8 bfr = *(const bf16x8*)&Ebuf[srow*256 + chunk*8];
        acc[0][j] = __builtin_amdgcn_mfma_f32_16x16x32_bf16(a0, bfr, acc[0][j], 0, 0, 0);
        acc[1][j] = __builtin_amdgcn_mfma_f32_16x16x32_bf16(a1, bfr, acc[1][j], 0, 0, 0);
      }
    }
    #pragma unroll
    for (int m=0;m<2;m++){
      #pragma unroll
      for (int j=0;j<4;j++){
        #pragma unroll
        for (int rr=0;rr<4;rr++){
          int o = o0 + m*16 + kg*4 + rr;
          int scol = j*16 + r;
          ew[((size_t)(b*256+o))*4096 + t*64 + scol] = f2bf(__expf(acc[m][j][rr] + b3[o]));
        }
      }
    }
  }
}

// ---------------------------------------------------------------- softmax+PV
// hv1[n][h][cq][t] (bf16): full 128B-line stores (t = lane dim).
// XCD swizzle: all 64 blocks of one (b,h) land on one XCD.
__global__ __launch_bounds__(256) void k_attn(
    const ushort* __restrict__ es, const ushort* __restrict__ ew,
    const ushort* __restrict__ qkv, ushort* __restrict__ hv1)
{
  int i = blockIdx.x;            // 1024
  int xcd = i & 7, j0 = i >> 3;  // j0 in [0,128)
  int g = xcd + ((j0 >> 6) << 3);  // (b*8+h) group, 0..15
  int w64 = j0 & 63;
  int b = g >> 3, hh = g & 7;
  int dq = w64 >> 3, cs = w64 & 7;
  int tid = threadIdx.x;
  int t  = tid & 63;
  int dj = __builtin_amdgcn_readfirstlane(tid >> 6);
  int n  = b*D_ + dq*4 + dj;
  __shared__ float4 ewl[64][16];   // [t][k^(t&15)] swizzled
  __shared__ float4 vl4[4][16];
  float4 esr[16];
  {
    const u16x8* sp = (const u16x8*)(es + ((size_t)(n*8 + hh))*4096 + (size_t)t*64);
    #pragma unroll
    for (int k8=0;k8<8;k8++){
      u16x8 e8 = sp[k8];
      float4 lo, hi;
      lo.x=bf2f(e8[0]); lo.y=bf2f(e8[1]); lo.z=bf2f(e8[2]); lo.w=bf2f(e8[3]);
      hi.x=bf2f(e8[4]); hi.y=bf2f(e8[5]); hi.z=bf2f(e8[6]); hi.w=bf2f(e8[7]);
      esr[2*k8] = lo; esr[2*k8+1] = hi;
    }
  }
  int vd = tid >> 4, vk = tid & 15;          // v stage coords (tid<64)
  u16x8 rew[2]; ushort4 rv;
  {
    int c = cs*32 + hh;
    const u16x8* wap = (const u16x8*)(ew + ((size_t)(b*256 + c))*4096);
    rew[0] = wap[tid]; rew[1] = wap[tid+256];
    if (tid < 64)
      rv = *(const ushort4*)(qkv + ((size_t)(b*D_ + dq*4 + vd)*768 + 512 + c)*64 + 4*vk);
  }
  for (int ci=0; ci<4; ci++){
    __syncthreads();
    #pragma unroll
    for (int i2=0;i2<2;i2++){
      int ch = tid + 256*i2;           // chunk of 8 ushorts
      int tr = ch >> 3, k8 = ch & 7;
      u16x8 e8 = rew[i2];
      float4 lo, hi;
      lo.x=bf2f(e8[0]); lo.y=bf2f(e8[1]); lo.z=bf2f(e8[2]); lo.w=bf2f(e8[3]);
      hi.x=bf2f(e8[4]); hi.y=bf2f(e8[5]); hi.z=bf2f(e8[6]); hi.w=bf2f(e8[7]);
      ewl[tr][(k8*2)   ^ (tr & 15)] = lo;
      ewl[tr][(k8*2+1) ^ (tr & 15)] = hi;
    }
    if (tid < 64){
      float4 vv; vv.x=bf2f(rv.x); vv.y=bf2f(rv.y); vv.z=bf2f(rv.z); vv.w=bf2f(rv.w);
      vl4[vd][vk] = vv;
    }
    __syncthreads();
    if (ci < 3){
      int c = (cs*4 + ci + 1)*8 + hh;
      const u16x8* wap = (const u16x8*)(ew + ((size_t)(b*256 + c))*4096);
      rew[0] = wap[tid]; rew[1] = wap[tid+256];
      if (tid < 64)
        rv = *(const ushort4*)(qkv + ((size_t)(b*D_ + dq*4 + vd)*768 + 512 + c)*64 + 4*vk);
    }
    float sum = 0.f;
    float ax=0.f, ay=0.f, az=0.f, aw=0.f;
    #pragma unroll
    for (int k=0;k<16;k++){
      float4 e4 = esr[k];
      float4 w4 = ewl[t][k ^ (t & 15)];
      float4 v4 = vl4[dj][k];
      float px = e4.x*w4.x, py = e4.y*w4.y, pz = e4.z*w4.z, pw = e4.w*w4.w;
      sum += px+py+pz+pw;
      ax = fmaf(px, v4.x, ax);
      ay = fmaf(py, v4.y, ay);
      az = fmaf(pz, v4.z, az);
      aw = fmaf(pw, v4.w, aw);
    }
    float acc = (ax+ay)+(az+aw);
    int cq = cs*4 + ci;
    hv1[(((size_t)n*8 + hh)*32 + cq)*64 + t] = f2bf(acc / sum);
  }
}

// ---------------------------------------------------------------- proj GEMM
// Out[n,o,t] fp32 = sum_K' Wr[o,K'] * hv1[n][h=K'>>5][cq=K'&31][t] + bias + x
// B-frag: 8 scalar u16 loads at 128B stride, wave-coalesced over t.
__global__ __launch_bounds__(256) void k_proj(
    const ushort* __restrict__ Wr, const ushort* __restrict__ hv1,
    const float* __restrict__ bias, const float* __restrict__ resid,
    float* __restrict__ Out)
{
  int blk = blockIdx.x;
  int n = blk >> 2, ob = blk & 3;
  int tid = threadIdx.x;
  int lane = tid & 63, w = tid >> 6;
  int o0 = ob*64 + w*16;
  int r = lane & 15, kg = lane >> 4;
  const ushort* wp = Wr + (size_t)(o0 + r)*256 + kg*8;
  f32x4 acc[4];
  #pragma unroll
  for (int j=0;j<4;j++) acc[j] = (f32x4){0.f,0.f,0.f,0.f};
  #pragma unroll
  for (int ks = 0; ks < 8; ks++) {       // ks = h
    bf16x8 a = *(const bf16x8*)(wp + ks*32);
    #pragma unroll
    for (int j = 0; j < 4; j++) {
      const ushort* bp = hv1 + (((size_t)n*8 + ks)*32 + kg*8)*64 + (j*16 + r);
      bf16x8 bfr;
      #pragma unroll
      for (int e=0;e<8;e++) bfr[e] = (short)bp[(size_t)e*64];
      acc[j] = __builtin_amdgcn_mfma_f32_16x16x32_bf16(a, bfr, acc[j], 0, 0, 0);
    }
  }
  #pragma unroll
  for (int j = 0; j < 4; j++) {
    #pragma unroll
    for (int rr = 0; rr < 4; rr++) {
      int o = o0 + kg*4 + rr;
      size_t idx = ((size_t)n*256 + o)*64 + j*16 + r;
      Out[idx] = acc[j][rr] + bias[o] + resid[idx];
    }
  }
}

extern "C" void kernel_launch(void* const* d_in, const int* in_sizes, int n_in,
                              void* d_out, int out_size, void* d_ws, size_t ws_size,
                              hipStream_t stream) {
  const float* x     = (const float*)d_in[0];
  const float* temb  = (const float*)d_in[1];
  const int*   fi    = (const int*)  d_in[2];
  const float* amask = (const float*)d_in[3];
  const float* nsc   = (const float*)d_in[4];
  const float* nbi   = (const float*)d_in[5];
  const float* w_qkv = (const float*)d_in[6];
  const float* b_qkv = (const float*)d_in[7];
  const float* w1    = (const float*)d_in[8];
  const float* b1    = (const float*)d_in[9];
  const float* w2    = (const float*)d_in[10];
  const float* b2    = (const float*)d_in[11];
  const float* w3    = (const float*)d_in[12];
  const float* b3    = (const float*)d_in[13];
  const float* wp    = (const float*)d_in[14];
  const float* bp    = (const float*)d_in[15];
  float* out = (float*)d_out;

  ushort* qkvb = (ushort*)d_ws;               // 3,145,728 us
  float*  tpb  = (float*)(qkvb + 3145728);    //    32,768 f
  ushort* esb  = (ushort*)(tpb + 32768);      // 2,097,152 us
  ushort* ewb  = esb + 2097152;               // 2,097,152 us
  ushort* htb  = ewb + 2097152;               // 1,048,576 us
  ushort* hvb  = htb + 1048576;               // 1,048,576 us
  ushort* wqb  = hvb + 1048576;               //   196,608 us
  ushort* wprb = wqb + 196608;                //    65,536 us
  ushort* w3b  = wprb + 65536;                //    65,536 us

  k_prep <<<2496, 256, 0, stream>>>(w_qkv, wp, w3, wqb, wprb, w3b,
                                    x, nsc, nbi, htb, temb, w2, b2, tpb);
  k_mm   <<<N_*12, 256, 0, stream>>>(wqb, htb, b_qkv, qkvb);
  k_sw   <<<768, 256, 0, stream>>>(qkvb, esb, amask, fi, w1, b1, tpb, w3b, b3, ewb);
  k_attn <<<B_*H_*8*8, 256, 0, stream>>>(esb, ewb, qkvb, hvb);
  k_proj <<<N_*4, 256, 0, stream>>>(wprb, hvb, bp, x, out);
}